// Round 19
// baseline (1096.068 us; speedup 1.0000x reference)
//
#include <hip/hip_runtime.h>
#include <math.h>

// N=4096, F_IN=512, Z=256, H=256, E=64, ATT=128, NPER=16, B=128
using f32x4 = __attribute__((ext_vector_type(4))) float;
using bf16x8 = __attribute__((ext_vector_type(8))) short;
#define MFMA16 __builtin_amdgcn_mfma_f32_16x16x32_bf16
static constexpr size_t M1c = 1048576;

__device__ __forceinline__ float wave_reduce_sum(float v) {
#pragma unroll
  for (int off = 32; off > 0; off >>= 1) v += __shfl_down(v, off);
  return v;
}

__device__ __forceinline__ unsigned short f2bf_rne(float x) {
  unsigned int u = __float_as_uint(x);
  unsigned int r = u + 0x7FFFu + ((u >> 16) & 1u);
  return (unsigned short)(r >> 16);
}
__device__ __forceinline__ void split1(float x, unsigned short& h, unsigned short& l) {
  unsigned int u = __float_as_uint(x);
  h = (unsigned short)(u >> 16);
  float rem = x - __uint_as_float(u & 0xFFFF0000u);
  l = f2bf_rne(rem);
}
__device__ __forceinline__ void split8(const float* f, bf16x8& h, bf16x8& l) {
#pragma unroll
  for (int i = 0; i < 8; ++i) {
    unsigned short hh, ll;
    split1(f[i], hh, ll);
    h[i] = (short)hh;
    l[i] = (short)ll;
  }
}

// ---------------------------------------------------------------------------
// Adjacency pass (vectorized float4); 1 row per wave, grid 1024
// ---------------------------------------------------------------------------
__global__ __launch_bounds__(256) void k_rowsums(
    const float* __restrict__ c0, const float* __restrict__ c1,
    const float* __restrict__ d0, const float* __restrict__ d1,
    const float* __restrict__ wb, float* __restrict__ tmp,
    float* __restrict__ rs_c0, float* __restrict__ rs_c1,
    float* __restrict__ rs_d0, float* __restrict__ rs_d1,
    float* __restrict__ dg_c0, float* __restrict__ dg_c1,
    float* __restrict__ dg_d0, float* __restrict__ dg_d1) {
  int wave = threadIdx.x >> 6, lane = threadIdx.x & 63;
  float hw0 = 0.5f * wb[0], hw1 = 0.5f * wb[1];
  int row = blockIdx.x * 4 + wave;
  const float4* pc0 = (const float4*)(c0 + (size_t)row * 4096);
  const float4* pc1 = (const float4*)(c1 + (size_t)row * 4096);
  const float4* pd0 = (const float4*)(d0 + (size_t)row * 4096);
  const float4* pd1 = (const float4*)(d1 + (size_t)row * 4096);
  float4* pt = (float4*)(tmp + (size_t)row * 4096);
  float s0 = 0.f, s1 = 0.f, s2 = 0.f, s3 = 0.f;
  int dq = row >> 2, dcomp = row & 3;
  for (int ct = 0; ct < 16; ++ct) {
    int c4 = ct * 64 + lane;
    float4 a = pc0[c4], b = pc1[c4], e = pd0[c4], f = pd1[c4];
    s0 += a.x + a.y + a.z + a.w;
    s1 += b.x + b.y + b.z + b.w;
    s2 += e.x + e.y + e.z + e.w;
    s3 += f.x + f.y + f.z + f.w;
    float4 t4;
    t4.x = hw0 * (a.x + b.x) + hw1 * (e.x + f.x);
    t4.y = hw0 * (a.y + b.y) + hw1 * (e.y + f.y);
    t4.z = hw0 * (a.z + b.z) + hw1 * (e.z + f.z);
    t4.w = hw0 * (a.w + b.w) + hw1 * (e.w + f.w);
    pt[c4] = t4;
    if (c4 == dq) {
      dg_c0[row] = dcomp == 0 ? a.x : dcomp == 1 ? a.y : dcomp == 2 ? a.z : a.w;
      dg_c1[row] = dcomp == 0 ? b.x : dcomp == 1 ? b.y : dcomp == 2 ? b.z : b.w;
      dg_d0[row] = dcomp == 0 ? e.x : dcomp == 1 ? e.y : dcomp == 2 ? e.z : e.w;
      dg_d1[row] = dcomp == 0 ? f.x : dcomp == 1 ? f.y : dcomp == 2 ? f.z : f.w;
    }
  }
  s0 = wave_reduce_sum(s0); s1 = wave_reduce_sum(s1);
  s2 = wave_reduce_sum(s2); s3 = wave_reduce_sum(s3);
  if (lane == 0) { rs_c0[row] = s0; rs_c1[row] = s1; rs_d0[row] = s2; rs_d1[row] = s3; }
}

// Column sums, vectorized: grid (4, 32); c4 = float4 column index
__global__ __launch_bounds__(256) void k_colsum(const float* __restrict__ T,
                                                float* __restrict__ cs) {
  int c4 = blockIdx.x * 256 + threadIdx.x;
  int r0 = blockIdx.y * 128;
  const float4* T4 = (const float4*)T;
  float4 a = make_float4(0.f, 0.f, 0.f, 0.f);
  for (int r = r0; r < r0 + 128; ++r) {
    float4 p = T4[(size_t)r * 1024 + c4];
    a.x += p.x; a.y += p.y; a.z += p.z; a.w += p.w;
  }
  atomicAdd(&cs[c4 * 4 + 0], a.x);
  atomicAdd(&cs[c4 * 4 + 1], a.y);
  atomicAdd(&cs[c4 * 4 + 2], a.z);
  atomicAdd(&cs[c4 * 4 + 3], a.w);
}

// A1n = d[row]*d[col]*(tmp + tmp^T) -> split-bf16 pair (float4/ushort4 path)
__global__ __launch_bounds__(256) void k_addTn(const float* __restrict__ T,
                                               const float* __restrict__ dv,
                                               unsigned short* __restrict__ A1h,
                                               unsigned short* __restrict__ A1l) {
  __shared__ float t[64][65];
  int bi = blockIdx.y, bj = blockIdx.x;
  int r = threadIdx.x >> 4;        // 0..15
  int c4 = threadIdx.x & 15;       // float4 col index within 64
#pragma unroll
  for (int rr = 0; rr < 4; ++rr) {
    int row = rr * 16 + r;
    float4 v = *(const float4*)(T + (size_t)(bj * 64 + row) * 4096 + bi * 64 + c4 * 4);
    t[row][c4 * 4 + 0] = v.x; t[row][c4 * 4 + 1] = v.y;
    t[row][c4 * 4 + 2] = v.z; t[row][c4 * 4 + 3] = v.w;
  }
  __syncthreads();
#pragma unroll
  for (int rr = 0; rr < 4; ++rr) {
    int ro = rr * 16 + r;
    int rowg = bi * 64 + ro;
    float dr = dv[rowg];
    size_t idx = (size_t)rowg * 4096 + bj * 64 + c4 * 4;
    float4 a = *(const float4*)(T + idx);
    float f0 = (a.x + t[c4 * 4 + 0][ro]) * dr * dv[bj * 64 + c4 * 4 + 0];
    float f1 = (a.y + t[c4 * 4 + 1][ro]) * dr * dv[bj * 64 + c4 * 4 + 1];
    float f2 = (a.z + t[c4 * 4 + 2][ro]) * dr * dv[bj * 64 + c4 * 4 + 2];
    float f3 = (a.w + t[c4 * 4 + 3][ro]) * dr * dv[bj * 64 + c4 * 4 + 3];
    ushort4 hv, lv;
    split1(f0, ((unsigned short*)&hv)[0], ((unsigned short*)&lv)[0]);
    split1(f1, ((unsigned short*)&hv)[1], ((unsigned short*)&lv)[1]);
    split1(f2, ((unsigned short*)&hv)[2], ((unsigned short*)&lv)[2]);
    split1(f3, ((unsigned short*)&hv)[3], ((unsigned short*)&lv)[3]);
    *(ushort4*)(A1h + idx) = hv;
    *(ushort4*)(A1l + idx) = lv;
  }
}

__global__ __launch_bounds__(256) void k_fin(
    const float* __restrict__ rs_c0, const float* __restrict__ rs_c1,
    const float* __restrict__ rs_d0, const float* __restrict__ rs_d1,
    const float* __restrict__ dg_c0, const float* __restrict__ dg_c1,
    const float* __restrict__ dg_d0, const float* __restrict__ dg_d1,
    const float* __restrict__ cs_tmp, const float* __restrict__ wb,
    float* __restrict__ d_c0, float* __restrict__ d_c1,
    float* __restrict__ d_dd0, float* __restrict__ d_dd1, float* __restrict__ d_A1,
    float* __restrict__ gP_dd0, float* __restrict__ gP_dd1, float* __restrict__ gP_A1) {
  int n = blockIdx.x * 256 + threadIdx.x;
  float rc0 = rs_c0[n], rc1 = rs_c1[n], rd0 = rs_d0[n], rd1 = rs_d1[n];
  float gc0 = dg_c0[n], gc1 = dg_c1[n], gd0 = dg_d0[n], gd1 = dg_d1[n];
  d_c0[n] = rsqrtf(fmaxf(rc0 - gc0 + 1.f, 1.f));
  d_c1[n] = rsqrtf(fmaxf(rc1 - gc1 + 1.f, 1.f));
  float cmr = 0.5f * (rc0 + rc1), cmg = 0.5f * (gc0 + gc1);
  float g0 = gd0 + cmg; gP_dd0[n] = g0;
  d_dd0[n] = rsqrtf(fmaxf(rd0 + cmr - g0 + 1.f, 1.f));
  float g1 = gd1 + cmg; gP_dd1[n] = g1;
  d_dd1[n] = rsqrtf(fmaxf(rd1 + cmr - g1 + 1.f, 1.f));
  float w0 = wb[0], w1 = wb[1];
  float rt = w0 * cmr + w1 * 0.5f * (rd0 + rd1);
  float gt = w0 * cmg + w1 * 0.5f * (gd0 + gd1);
  gP_A1[n] = 2.f * gt;
  d_A1[n] = rsqrtf(fmaxf(rt + cs_tmp[n] - 2.f * gt + 1.f, 1.f));
}

__global__ __launch_bounds__(256) void k_dA2(const float* __restrict__ rs,
                                             const float* __restrict__ gP,
                                             float* __restrict__ dvec) {
  int n = blockIdx.x * 256 + threadIdx.x;
  dvec[n] = rsqrtf(fmaxf(rs[n] - gP[n] + 1.f, 1.f));
}

// cn rows -> split bf16 pair [4096][1024], both contexts in one dispatch
__global__ __launch_bounds__(256) void k_cn2(
    const float* __restrict__ mu_c, const float* __restrict__ Wt_c,
    const float* __restrict__ mu_d, const float* __restrict__ Wt_d,
    unsigned short* __restrict__ Cch, unsigned short* __restrict__ Ccl,
    unsigned short* __restrict__ Cdh, unsigned short* __restrict__ Cdl) {
  int g = blockIdx.x * 4 + (threadIdx.x >> 6);
  int lane = threadIdx.x & 63;
  bool dsel = g >= 65536;
  int gg = dsel ? g - 65536 : g;
  const float* mu = dsel ? mu_d : mu_c;
  const float* Wt = dsel ? Wt_d : Wt_c;
  unsigned short* Oh = dsel ? Cdh : Cch;
  unsigned short* Ol = dsel ? Cdl : Ccl;
  int n = gg >> 4, p = gg & 15;
  float v = mu[(size_t)n * 64 + lane] * Wt[p * 64 + lane];
  float ss = v * v;
#pragma unroll
  for (int off = 32; off > 0; off >>= 1) ss += __shfl_xor(ss, off);
  float nrm = fmaxf(sqrtf(ss), 1e-12f);
  float r = v / nrm;
  unsigned short h, l;
  split1(r, h, l);
  size_t o = (size_t)n * 1024 + p * 64 + lane;
  Oh[o] = h; Ol[o] = l;
}

// ---------------------------------------------------------------------------
// prepB: X [K][C] fp32 (optional per-k scale) -> Bt hi/lo bf16 [C][K]
// ---------------------------------------------------------------------------
__global__ __launch_bounds__(256) void k_prepB(const float* __restrict__ X,
                                               const float* __restrict__ scale,
                                               unsigned short* __restrict__ Bh,
                                               unsigned short* __restrict__ Bl,
                                               int K, int C) {
  __shared__ float t[64][65];
  int kb = blockIdx.x * 64, cb = blockIdx.y * 64;
  int lane = threadIdx.x & 63, w = threadIdx.x >> 6;
  for (int i = 0; i < 16; ++i) {
    int kk = w * 16 + i;
    float s = scale ? scale[kb + kk] : 1.f;
    t[kk][lane] = X[(size_t)(kb + kk) * C + cb + lane] * s;
  }
  __syncthreads();
  for (int i = 0; i < 16; ++i) {
    int cc = w * 16 + i;
    float v = t[lane][cc];
    unsigned short h, l;
    split1(v, h, l);
    size_t o = (size_t)(cb + cc) * K + kb + lane;
    Bh[o] = h; Bl[o] = l;
  }
}

// ---------------------------------------------------------------------------
// Fused 4-segment GEMM, BM=64 x BN=256, BK=64 pair-step pipeline, partials.
// 1-D grid with XCD-aware bijective swizzle: gridDim.x = 4*KS*64 (%8==0).
// ---------------------------------------------------------------------------
__global__ __launch_bounds__(256) void k_prop4S(
    const float* __restrict__ As0, const float* __restrict__ As1,
    const float* __restrict__ As2, const float* __restrict__ As3,
    const float* __restrict__ Ax0, const float* __restrict__ Ax1, int cmask,
    const float* __restrict__ dsc0, const float* __restrict__ dsc1,
    const float* __restrict__ dsc2, const float* __restrict__ dsc3,
    const unsigned short* __restrict__ B0h, const unsigned short* __restrict__ B0l,
    const unsigned short* __restrict__ B1h, const unsigned short* __restrict__ B1l,
    const unsigned short* __restrict__ B2h, const unsigned short* __restrict__ B2l,
    const unsigned short* __restrict__ B3h, const unsigned short* __restrict__ B3l,
    float* __restrict__ part, int K, int Kc, int KS) {
  int d = blockIdx.x;
  int q = gridDim.x >> 3;
  int lin = (d & 7) * q + (d >> 3);
  int mblk = lin & 63;
  int sk = lin >> 6;
  int seg = sk / KS, kb = sk % KS;
  const float* A = seg == 0 ? As0 : seg == 1 ? As1 : seg == 2 ? As2 : As3;
  const unsigned short* Bh = seg == 0 ? B0h : seg == 1 ? B1h : seg == 2 ? B2h : B3h;
  const unsigned short* Bl = seg == 0 ? B0l : seg == 1 ? B1l : seg == 2 ? B2l : B3l;
  const float* dsc = seg == 0 ? dsc0 : seg == 1 ? dsc1 : seg == 2 ? dsc2 : dsc3;
  const bool usecm = (cmask >> seg) & 1;
  const bool usesc = dsc != nullptr;
  __shared__ unsigned char sm[2][2][8192];  // [pairbuf][half][64 rows x 128B]
  const int tid = threadIdx.x;
  const int m0 = mblk * 64, k0 = kb * Kc;
  const int w = tid >> 6, lane = tid & 63;
  const int lr = lane & 15, lk = (lane >> 4) * 8, n0w = w * 64;
  const int srow = tid >> 2, skp = (tid & 3) * 8;
  const int swz = (srow & 7) << 4;
  const int offh = (srow * 128 + skp * 2) ^ swz;
  const int offl = (srow * 128 + 64 + skp * 2) ^ swz;
  const size_t rowoff = (size_t)(m0 + srow) * K + k0 + skp;
  const float* arow = A + rowoff;
  const float* xrow0 = Ax0 + rowoff;
  const float* xrow1 = Ax1 + rowoff;
  const float* scrow = usesc ? (dsc + k0 + skp) : nullptr;

  float4 xa0, xa1, xb0, xb1;
  float4 ya0, ya1, yb0, yb1;
  float4 za0, za1, zb0, zb1;
  float4 sa0, sa1, sb0, sb1;
  auto ldPair = [&](int kk) {
    xa0 = *(const float4*)(arow + kk);
    xa1 = *(const float4*)(arow + kk + 4);
    xb0 = *(const float4*)(arow + kk + 32);
    xb1 = *(const float4*)(arow + kk + 36);
    if (usecm) {
      ya0 = *(const float4*)(xrow0 + kk);
      ya1 = *(const float4*)(xrow0 + kk + 4);
      yb0 = *(const float4*)(xrow0 + kk + 32);
      yb1 = *(const float4*)(xrow0 + kk + 36);
      za0 = *(const float4*)(xrow1 + kk);
      za1 = *(const float4*)(xrow1 + kk + 4);
      zb0 = *(const float4*)(xrow1 + kk + 32);
      zb1 = *(const float4*)(xrow1 + kk + 36);
    }
    if (usesc) {
      sa0 = *(const float4*)(scrow + kk);
      sa1 = *(const float4*)(scrow + kk + 4);
      sb0 = *(const float4*)(scrow + kk + 32);
      sb1 = *(const float4*)(scrow + kk + 36);
    }
  };
  auto wrPair = [&](int pb) {
    {
      float f[8] = {xa0.x, xa0.y, xa0.z, xa0.w, xa1.x, xa1.y, xa1.z, xa1.w};
      if (usecm) {
        f[0] += 0.5f * (ya0.x + za0.x); f[1] += 0.5f * (ya0.y + za0.y);
        f[2] += 0.5f * (ya0.z + za0.z); f[3] += 0.5f * (ya0.w + za0.w);
        f[4] += 0.5f * (ya1.x + za1.x); f[5] += 0.5f * (ya1.y + za1.y);
        f[6] += 0.5f * (ya1.z + za1.z); f[7] += 0.5f * (ya1.w + za1.w);
      }
      if (usesc) {
        f[0] *= sa0.x; f[1] *= sa0.y; f[2] *= sa0.z; f[3] *= sa0.w;
        f[4] *= sa1.x; f[5] *= sa1.y; f[6] *= sa1.z; f[7] *= sa1.w;
      }
      bf16x8 hh, ll;
      split8(f, hh, ll);
      *(bf16x8*)(&sm[pb][0][0] + offh) = hh;
      *(bf16x8*)(&sm[pb][0][0] + offl) = ll;
    }
    {
      float f[8] = {xb0.x, xb0.y, xb0.z, xb0.w, xb1.x, xb1.y, xb1.z, xb1.w};
      if (usecm) {
        f[0] += 0.5f * (yb0.x + zb0.x); f[1] += 0.5f * (yb0.y + zb0.y);
        f[2] += 0.5f * (yb0.z + zb0.z); f[3] += 0.5f * (yb0.w + zb0.w);
        f[4] += 0.5f * (yb1.x + zb1.x); f[5] += 0.5f * (yb1.y + zb1.y);
        f[6] += 0.5f * (yb1.z + zb1.z); f[7] += 0.5f * (yb1.w + zb1.w);
      }
      if (usesc) {
        f[0] *= sb0.x; f[1] *= sb0.y; f[2] *= sb0.z; f[3] *= sb0.w;
        f[4] *= sb1.x; f[5] *= sb1.y; f[6] *= sb1.z; f[7] *= sb1.w;
      }
      bf16x8 hh, ll;
      split8(f, hh, ll);
      *(bf16x8*)(&sm[pb][1][0] + offh) = hh;
      *(bf16x8*)(&sm[pb][1][0] + offl) = ll;
    }
  };

  f32x4 acc[4][4] = {};
  auto comp = [&](int pb, int half, int kkg) {
    const unsigned char* base = &sm[pb][half][0];
    bf16x8 ah[4], al[4];
#pragma unroll
    for (int i = 0; i < 4; ++i) {
      int row = i * 16 + lr, sz = (row & 7) << 4;
      ah[i] = *(const bf16x8*)(base + ((row * 128 + lk * 2) ^ sz));
      al[i] = *(const bf16x8*)(base + ((row * 128 + 64 + lk * 2) ^ sz));
    }
#pragma unroll
    for (int j = 0; j < 4; ++j) {
      int col = n0w + j * 16 + lr;
      size_t bo = (size_t)col * K + kkg;
      bf16x8 bh = *(const bf16x8*)(Bh + bo);
      bf16x8 bl = *(const bf16x8*)(Bl + bo);
#pragma unroll
      for (int i = 0; i < 4; ++i) {
        acc[i][j] = MFMA16(ah[i], bh, acc[i][j], 0, 0, 0);
        acc[i][j] = MFMA16(ah[i], bl, acc[i][j], 0, 0, 0);
        acc[i][j] = MFMA16(al[i], bh, acc[i][j], 0, 0, 0);
      }
    }
  };

  int pairs = Kc / 64;
  ldPair(0);
  wrPair(0);
  __syncthreads();
  for (int p = 0; p < pairs; ++p) {
    if (p + 1 < pairs) ldPair((p + 1) * 64);
    comp(p & 1, 0, k0 + p * 64 + lk);
    comp(p & 1, 1, k0 + p * 64 + 32 + lk);
    if (p + 1 < pairs) wrPair((p + 1) & 1);
    __syncthreads();
  }
  int rr = (lane >> 4) * 4;
  float* Cp = part + (size_t)(seg * KS + kb) * M1c;
#pragma unroll
  for (int i = 0; i < 4; ++i)
#pragma unroll
    for (int j = 0; j < 4; ++j) {
      int col = n0w + j * 16 + lr;
#pragma unroll
      for (int r = 0; r < 4; ++r)
        Cp[(size_t)(m0 + i * 16 + rr + r) * 256 + col] = acc[i][j][r];
    }
}

// ---------------------------------------------------------------------------
// Single planar-pair GEMM, BM=32 x BN=256, BK=64 pair-step, DEPTH-2 prefetch.
// acc[2][4] (32 AGPR) + 16 KB LDS -> high occupancy. grid = KS*128 (%8==0).
// ---------------------------------------------------------------------------
__global__ __launch_bounds__(256) void k_gemmS(
    const unsigned short* __restrict__ Ah, const unsigned short* __restrict__ Al,
    const unsigned short* __restrict__ Bth, const unsigned short* __restrict__ Btl,
    float* __restrict__ part, int K, int Kc) {
  int d = blockIdx.x;
  int q = gridDim.x >> 3;
  int lin = (d & 7) * q + (d >> 3);
  int mblk = lin & 127;
  int kb = lin >> 7;
  __shared__ unsigned char sm[2][2][4096];  // [pairbuf][half][32 rows x 128B]
  const int tid = threadIdx.x;
  const int m0 = mblk * 32, k0 = kb * Kc;
  const int w = tid >> 6, lane = tid & 63;
  const int lr = lane & 15, lk = (lane >> 4) * 8, n0w = w * 64;
  const int srow = tid >> 3;        // 0..31
  const int skp8 = (tid & 7) * 8;   // 0..56 (element offset within 64-k pair)
  const int half = (tid & 7) >> 2;  // 0: k 0-31, 1: k 32-63
  const int kin = skp8 & 31;        // 0..24
  const int swz = (srow & 7) << 4;
  const int offh = (srow * 128 + kin * 2) ^ swz;
  const int offl = (srow * 128 + 64 + kin * 2) ^ swz;
  const unsigned short* arh = Ah + (size_t)(m0 + srow) * K + k0 + skp8;
  const unsigned short* arl = Al + (size_t)(m0 + srow) * K + k0 + skp8;

  // two named register sets: even pairs -> r*, odd pairs -> s*
  bf16x8 rh, rl, sh, sl;
  auto ld0 = [&](int kk) {
    rh = *(const bf16x8*)(arh + kk);
    rl = *(const bf16x8*)(arl + kk);
  };
  auto ld1 = [&](int kk) {
    sh = *(const bf16x8*)(arh + kk);
    sl = *(const bf16x8*)(arl + kk);
  };
  auto wr0 = [&](int pb) {
    *(bf16x8*)(&sm[pb][half][0] + offh) = rh;
    *(bf16x8*)(&sm[pb][half][0] + offl) = rl;
  };
  auto wr1 = [&](int pb) {
    *(bf16x8*)(&sm[pb][half][0] + offh) = sh;
    *(bf16x8*)(&sm[pb][half][0] + offl) = sl;
  };

  f32x4 acc[2][4] = {};
  auto comp = [&](int pb, int hf, int kkg) {
    const unsigned char* base = &sm[pb][hf][0];
    bf16x8 ah[2], al[2];
#pragma unroll
    for (int i = 0; i < 2; ++i) {
      int row = i * 16 + lr, sz = (row & 7) << 4;
      ah[i] = *(const bf16x8*)(base + ((row * 128 + lk * 2) ^ sz));
      al[i] = *(const bf16x8*)(base + ((row * 128 + 64 + lk * 2) ^ sz));
    }
#pragma unroll
    for (int j = 0; j < 4; ++j) {
      int col = n0w + j * 16 + lr;
      size_t bo = (size_t)col * K + kkg;
      bf16x8 bh = *(const bf16x8*)(Bth + bo);
      bf16x8 bl = *(const bf16x8*)(Btl + bo);
#pragma unroll
      for (int i = 0; i < 2; ++i) {
        acc[i][j] = MFMA16(ah[i], bh, acc[i][j], 0, 0, 0);
        acc[i][j] = MFMA16(ah[i], bl, acc[i][j], 0, 0, 0);
        acc[i][j] = MFMA16(al[i], bh, acc[i][j], 0, 0, 0);
      }
    }
  };

  int pairs = Kc / 64;
  ld0(0);
  wr0(0);
  if (pairs > 1) ld1(64);
  __syncthreads();
  for (int p = 0; p < pairs; ++p) {
    if (p + 2 < pairs) {
      if ((p & 1) == 0) ld0((p + 2) * 64); else ld1((p + 2) * 64);
    }
    comp(p & 1, 0, k0 + p * 64 + lk);
    comp(p & 1, 1, k0 + p * 64 + 32 + lk);
    if (p + 1 < pairs) {
      if (((p + 1) & 1) == 0) wr0((p + 1) & 1); else wr1((p + 1) & 1);
    }
    __syncthreads();
  }
  int rr = (lane >> 4) * 4;
  float* Cp = part + (size_t)kb * M1c;
#pragma unroll
  for (int i = 0; i < 2; ++i)
#pragma unroll
    for (int j = 0; j < 4; ++j) {
      int col = n0w + j * 16 + lr;
#pragma unroll
      for (int r = 0; r < 4; ++r)
        Cp[(size_t)(m0 + i * 16 + rr + r) * 256 + col] = acc[i][j][r];
    }
}

// ---------------------------------------------------------------------------
// Heads GEMM: dual fp32 A (waves 0-1 Aa, 2-3 Ab), BM=64, partial out.
// grid (4, 64), K=256, Kc=64.
// ---------------------------------------------------------------------------
__global__ __launch_bounds__(256) void k_gemmH(
    const float* __restrict__ Aa, const float* __restrict__ Ab,
    const unsigned short* __restrict__ Bth, const unsigned short* __restrict__ Btl,
    float* __restrict__ part, int K, int Kc) {
  __shared__ unsigned char sm[2][2][8192];
  const int tid = threadIdx.x;
  const int m0 = blockIdx.y * 64, k0 = blockIdx.x * Kc;
  const int w = tid >> 6, lane = tid & 63;
  const int lr = lane & 15, lk = (lane >> 4) * 8, n0w = w * 64;
  const int srow = tid >> 2, skp = (tid & 3) * 8;
  const int swz = (srow & 7) << 4;
  const int offh = (srow * 128 + skp * 2) ^ swz;
  const int offl = (srow * 128 + 64 + skp * 2) ^ swz;
  const int slot = w >> 1;

  auto stage = [&](int b, int kk) {
    int kg = k0 + kk + skp;
    const float* p = Aa + (size_t)(m0 + srow) * K + kg;
    float4 x0 = *(const float4*)(p), x1 = *(const float4*)(p + 4);
    float f[8] = {x0.x, x0.y, x0.z, x0.w, x1.x, x1.y, x1.z, x1.w};
    bf16x8 hh, ll;
    split8(f, hh, ll);
    *(bf16x8*)(&sm[b][0][0] + offh) = hh;
    *(bf16x8*)(&sm[b][0][0] + offl) = ll;
    const float* qq = Ab + (size_t)(m0 + srow) * K + kg;
    float4 y0 = *(const float4*)(qq), y1 = *(const float4*)(qq + 4);
    float g[8] = {y0.x, y0.y, y0.z, y0.w, y1.x, y1.y, y1.z, y1.w};
    split8(g, hh, ll);
    *(bf16x8*)(&sm[b][1][0] + offh) = hh;
    *(bf16x8*)(&sm[b][1][0] + offl) = ll;
  };

  f32x4 acc[4][4] = {};
  stage(0, 0);
  __syncthreads();
  int steps = Kc / 32;
  for (int s = 0; s < steps; ++s) {
    if (s + 1 < steps) stage((s + 1) & 1, (s + 1) * 32);
    const unsigned char* base = &sm[s & 1][slot][0];
    bf16x8 ah[4], al[4];
#pragma unroll
    for (int i = 0; i < 4; ++i) {
      int row = i * 16 + lr, sz = (row & 7) << 4;
      ah[i] = *(const bf16x8*)(base + ((row * 128 + lk * 2) ^ sz));
      al[i] = *(const bf16x8*)(base + ((row * 128 + 64 + lk * 2) ^ sz));
    }
    int kkg = k0 + s * 32 + lk;
#pragma unroll
    for (int j = 0; j < 4; ++j) {
      int col = n0w + j * 16 + lr;
      size_t bo = (size_t)col * K + kkg;
      bf16x8 bh = *(const bf16x8*)(Bth + bo);
      bf16x8 bl = *(const bf16x8*)(Btl + bo);
#pragma unroll
      for (int i = 0; i < 4; ++i) {
        acc[i][j] = MFMA16(ah[i], bh, acc[i][j], 0, 0, 0);
        acc[i][j] = MFMA16(ah[i], bl, acc[i][j], 0, 0, 0);
        acc[i][j] = MFMA16(al[i], bh, acc[i][j], 0, 0, 0);
      }
    }
    __syncthreads();
  }
  int rr = (lane >> 4) * 4;
  float* Cp = part + (size_t)blockIdx.x * M1c;
#pragma unroll
  for (int i = 0; i < 4; ++i)
#pragma unroll
    for (int j = 0; j < 4; ++j) {
      int col = n0w + j * 16 + lr;
#pragma unroll
      for (int r = 0; r < 4; ++r)
        Cp[(size_t)(m0 + i * 16 + rr + r) * 256 + col] = acc[i][j][r];
    }
}

// ---------------------------------------------------------------------------
// Attention scoring GEMM: s_out[g] += sum tanh(z@W1 + b1)·w2, fused epilogue.
// grid (64, 6): g = (z,W) pair; BM=64, BN=128 (4 waves x 32 cols), K=256.
// ---------------------------------------------------------------------------
__global__ __launch_bounds__(256) void k_attG(
    const float* __restrict__ cr0, const float* __restrict__ cr1,
    const float* __restrict__ dr0, const float* __restrict__ dr1,
    const unsigned short* __restrict__ Wch, const unsigned short* __restrict__ Wcl,
    const unsigned short* __restrict__ Wdh, const unsigned short* __restrict__ Wdl,
    const float* __restrict__ bc1, const float* __restrict__ wc2,
    const float* __restrict__ bd1, const float* __restrict__ wd2,
    float* __restrict__ s_out) {
  int g = blockIdx.y;
  const float* A = g == 0 ? cr0 : g == 1 ? cr1 : g == 2 ? cr0 : g == 3 ? cr1
                                : g == 4 ? dr0 : dr1;
  const unsigned short* Bh = (g < 2) ? Wch : Wdh;
  const unsigned short* Bl = (g < 2) ? Wcl : Wdl;
  const float* b1 = (g < 2) ? bc1 : bd1;
  const float* w2 = (g < 2) ? wc2 : wd2;
  __shared__ unsigned char sm[2][8192];
  const int tid = threadIdx.x;
  const int m0 = blockIdx.x * 64;
  const int w = tid >> 6, lane = tid & 63;
  const int lr = lane & 15, lk = (lane >> 4) * 8, n0w = w * 32;
  const int srow = tid >> 2, skp = (tid & 3) * 8;
  const int swz = (srow & 7) << 4;
  const int offh = (srow * 128 + skp * 2) ^ swz;
  const int offl = (srow * 128 + 64 + skp * 2) ^ swz;

  auto stage = [&](int b, int kk) {
    const float* p = A + (size_t)(m0 + srow) * 256 + kk + skp;
    float4 x0 = *(const float4*)(p), x1 = *(const float4*)(p + 4);
    float f[8] = {x0.x, x0.y, x0.z, x0.w, x1.x, x1.y, x1.z, x1.w};
    bf16x8 hh, ll;
    split8(f, hh, ll);
    *(bf16x8*)(&sm[b][0] + offh) = hh;
    *(bf16x8*)(&sm[b][0] + offl) = ll;
  };

  f32x4 acc[4][2] = {};
  stage(0, 0);
  __syncthreads();
  for (int s = 0; s < 8; ++s) {
    if (s + 1 < 8) stage((s + 1) & 1, (s + 1) * 32);
    const unsigned char* base = &sm[s & 1][0];
    bf16x8 ah[4], al[4];
#pragma unroll
    for (int i = 0; i < 4; ++i) {
      int row = i * 16 + lr, sz = (row & 7) << 4;
      ah[i] = *(const bf16x8*)(base + ((row * 128 + lk * 2) ^ sz));
      al[i] = *(const bf16x8*)(base + ((row * 128 + 64 + lk * 2) ^ sz));
    }
    int kkg = s * 32 + lk;
#pragma unroll
    for (int j = 0; j < 2; ++j) {
      int col = n0w + j * 16 + lr;
      size_t bo = (size_t)col * 256 + kkg;
      bf16x8 bh = *(const bf16x8*)(Bh + bo);
      bf16x8 bl = *(const bf16x8*)(Bl + bo);
#pragma unroll
      for (int i = 0; i < 4; ++i) {
        acc[i][j] = MFMA16(ah[i], bh, acc[i][j], 0, 0, 0);
        acc[i][j] = MFMA16(ah[i], bl, acc[i][j], 0, 0, 0);
        acc[i][j] = MFMA16(al[i], bh, acc[i][j], 0, 0, 0);
      }
    }
    __syncthreads();
  }
  float tot = 0.f;
#pragma unroll
  for (int j = 0; j < 2; ++j) {
    int col = n0w + j * 16 + lr;
    float bb = b1[col], ww = w2[col];
#pragma unroll
    for (int i = 0; i < 4; ++i)
#pragma unroll
      for (int r = 0; r < 4; ++r) tot += tanhf(acc[i][j][r] + bb) * ww;
  }
  tot = wave_reduce_sum(tot);
  if (lane == 0) atomicAdd(&s_out[g], tot);
}

// ---------------------------------------------------------------------------
// Symmetric dual-Gram + A2 epilogue, both tiles LDS, split ld/wr (T14).
// 1-D grid of 528 upper-tri 128x128 blocks, XCD-bijective swizzle (528%8==0).
// ---------------------------------------------------------------------------
__global__ __launch_bounds__(256, 2) void k_cos2(
    const unsigned short* __restrict__ Ch, const unsigned short* __restrict__ Cl,
    const unsigned short* __restrict__ Dh, const unsigned short* __restrict__ Dl,
    const float* __restrict__ wb, float* __restrict__ rs, float* __restrict__ gP,
    unsigned short* __restrict__ A2h, unsigned short* __restrict__ A2l) {
  int dd = blockIdx.x;
  int b = (dd & 7) * 66 + (dd >> 3);
  int bi = 0, rem = b;
  while (rem >= 32 - bi) { rem -= 32 - bi; ++bi; }
  int bj = bi + rem;
  __shared__ unsigned char sm[2][2][16384];
  const int tid = threadIdx.x;
  const int w = tid >> 6, lane = tid & 63, wm = w >> 1, wn = w & 1;
  const int lr = lane & 15, lk = (lane >> 4) * 8;
  const int rbase = bi * 128, cbase = bj * 128;
  const int row0 = tid >> 2, kp = (tid & 3) * 8;

  auto ldT = [&](const unsigned short* Mh, const unsigned short* Ml, int br, int kk,
                 bf16x8* r) {
#pragma unroll
    for (int ss = 0; ss < 2; ++ss) {
      int row = row0 + ss * 64;
      size_t go = (size_t)(br + row) * 1024 + kk + kp;
      r[ss * 2] = *(const bf16x8*)(Mh + go);
      r[ss * 2 + 1] = *(const bf16x8*)(Ml + go);
    }
  };
  auto wrT = [&](int bb2, int t01, bf16x8* r) {
#pragma unroll
    for (int ss = 0; ss < 2; ++ss) {
      int row = row0 + ss * 64, sz = (row & 7) << 4;
      unsigned char* base = &sm[bb2][t01][0];
      *(bf16x8*)(base + ((row * 128 + kp * 2) ^ sz)) = r[ss * 2];
      *(bf16x8*)(base + ((row * 128 + 64 + kp * 2) ^ sz)) = r[ss * 2 + 1];
    }
  };
  auto gram = [&](const unsigned short* Mh, const unsigned short* Ml, f32x4 (&acc)[4][4]) {
    bf16x8 rA[4], rB[4];
    ldT(Mh, Ml, rbase, 0, rA);
    ldT(Mh, Ml, cbase, 0, rB);
    wrT(0, 0, rA);
    wrT(0, 1, rB);
    __syncthreads();
    for (int s = 0; s < 32; ++s) {
      if (s + 1 < 32) {
        ldT(Mh, Ml, rbase, (s + 1) * 32, rA);
        ldT(Mh, Ml, cbase, (s + 1) * 32, rB);
      }
      const unsigned char* ba = &sm[s & 1][0][0];
      const unsigned char* bb = &sm[s & 1][1][0];
      bf16x8 ah[4], al[4];
#pragma unroll
      for (int i = 0; i < 4; ++i) {
        int row = wm * 64 + i * 16 + lr;
        int sz = (row & 7) << 4;
        ah[i] = *(const bf16x8*)(ba + ((row * 128 + lk * 2) ^ sz));
        al[i] = *(const bf16x8*)(ba + ((row * 128 + 64 + lk * 2) ^ sz));
      }
#pragma unroll
      for (int j = 0; j < 4; ++j) {
        int rowb = wn * 64 + j * 16 + lr;
        int sz = (rowb & 7) << 4;
        bf16x8 bh = *(const bf16x8*)(bb + ((rowb * 128 + lk * 2) ^ sz));
        bf16x8 bl = *(const bf16x8*)(bb + ((rowb * 128 + 64 + lk * 2) ^ sz));
#pragma unroll
        for (int i = 0; i < 4; ++i) {
          acc[i][j] = MFMA16(ah[i], bh, acc[i][j], 0, 0, 0);
          acc[i][j] = MFMA16(ah[i], bl, acc[i][j], 0, 0, 0);
          acc[i][j] = MFMA16(al[i], bh, acc[i][j], 0, 0, 0);
        }
      }
      if (s + 1 < 32) {
        wrT((s + 1) & 1, 0, rA);
        wrT((s + 1) & 1, 1, rB);
      }
      __syncthreads();
    }
  };

  f32x4 aC[4][4] = {}, aD[4][4] = {};
  gram(Ch, Cl, aC);
  gram(Dh, Dl, aD);

  float w0 = wb[0] * 0.125f, w1 = wb[1] * 0.125f;
  int rr = (lane >> 4) * 4;
  bool diag = (bi == bj);
#pragma unroll
  for (int i = 0; i < 4; ++i) {
#pragma unroll
    for (int r = 0; r < 4; ++r) {
      int row = rbase + wm * 64 + i * 16 + rr + r;
      float p = 0.f;
#pragma unroll
      for (int j = 0; j < 4; ++j) {
        int col = cbase + wn * 64 + j * 16 + lr;
        float v = w0 * fmaxf(aC[i][j][r], 0.f) + w1 * fmaxf(aD[i][j][r], 0.f);
        p += v;
        unsigned short h, l;
        split1(v, h, l);
        size_t o = (size_t)row * 4096 + col;
        A2h[o] = h; A2l[o] = l;
        if (diag && row == col) gP[row] = v;
      }
      p += __shfl_xor(p, 1); p += __shfl_xor(p, 2);
      p += __shfl_xor(p, 4); p += __shfl_xor(p, 8);
      if (lr == 0) atomicAdd(&rs[row], p);
    }
  }
  if (!diag) {
#pragma unroll
    for (int j = 0; j < 4; ++j) {
      int col = cbase + wn * 64 + j * 16 + lr;
      float cs = 0.f;
#pragma unroll
      for (int i = 0; i < 4; ++i) {
        int row0m = rbase + wm * 64 + i * 16 + rr;
        ushort4 hv, lv;
#pragma unroll
        for (int r = 0; r < 4; ++r) {
          float v = w0 * fmaxf(aC[i][j][r], 0.f) + w1 * fmaxf(aD[i][j][r], 0.f);
          cs += v;
          unsigned short h, l;
          split1(v, h, l);
          ((unsigned short*)&hv)[r] = h;
          ((unsigned short*)&lv)[r] = l;
        }
        *(ushort4*)(A2h + (size_t)col * 4096 + row0m) = hv;
        *(ushort4*)(A2l + (size_t)col * 4096 + row0m) = lv;
      }
      cs += __shfl_xor(cs, 16); cs += __shfl_xor(cs, 32);
      if (lane < 16) atomicAdd(&rs[col], cs);
    }
  }
}

// ---------------------------------------------------------------------------
// Reduce + epilogue kernels (partials, no atomics)
// ---------------------------------------------------------------------------
__global__ __launch_bounds__(256) void k_redxw(
    const float* __restrict__ part, float* __restrict__ o0, float* __restrict__ o1,
    float* __restrict__ o2, float* __restrict__ o3) {
  int idx = blockIdx.x * 256 + threadIdx.x;
  size_t i4 = (size_t)idx * 4;
  int seg = (int)(i4 >> 20);
  size_t local = i4 & (M1c - 1);
  float4 a = make_float4(0.f, 0.f, 0.f, 0.f);
#pragma unroll
  for (int kb = 0; kb < 2; ++kb) {
    float4 p = *(const float4*)(part + (size_t)(seg * 2 + kb) * M1c + local);
    a.x += p.x; a.y += p.y; a.z += p.z; a.w += p.w;
  }
  float* o = seg == 0 ? o0 : seg == 1 ? o1 : seg == 2 ? o2 : o3;
  *(float4*)(o + local) = a;
}

// adj props: 4 segs x 2 partials + GCN epilogue (KS=2)
__global__ __launch_bounds__(256) void k_ep_prop4(
    const float* __restrict__ part, const float* __restrict__ xwc,
    const float* __restrict__ xwd, const float* __restrict__ dv0,
    const float* __restrict__ dv1, const float* __restrict__ dv2,
    const float* __restrict__ dv3, const float* __restrict__ dg0,
    const float* __restrict__ dg1, const float* __restrict__ dg2,
    const float* __restrict__ dg3, const float* __restrict__ bc,
    const float* __restrict__ bd, float* __restrict__ o0, float* __restrict__ o1,
    float* __restrict__ o2, float* __restrict__ o3) {
  int idx = blockIdx.x * 256 + threadIdx.x;
  size_t i4 = (size_t)idx * 4;
  int seg = (int)(i4 >> 20);
  size_t local = i4 & (M1c - 1);
  int row = (int)(local >> 8), c = (int)(local & 255);
  float4 a = make_float4(0.f, 0.f, 0.f, 0.f);
#pragma unroll
  for (int kb = 0; kb < 2; ++kb) {
    float4 p = *(const float4*)(part + (size_t)(seg * 2 + kb) * M1c + local);
    a.x += p.x; a.y += p.y; a.z += p.z; a.w += p.w;
  }
  const float* xw = (seg < 2) ? xwc : xwd;
  const float* dvec = seg == 0 ? dv0 : seg == 1 ? dv1 : seg == 2 ? dv2 : dv3;
  const float* dgp = seg == 0 ? dg0 : seg == 1 ? dg1 : seg == 2 ? dg2 : dg3;
  const float* bias = (seg < 2) ? bc : bd;
  float* out = seg == 0 ? o0 : seg == 1 ? o1 : seg == 2 ? o2 : o3;
  float4 x = *(const float4*)(xw + local);
  float4 b = *(const float4*)(bias + c);
  float dn = dvec[row], dfix = (1.f - dgp[row]) * dn * dn;
  float4 o;
  o.x = fmaxf(dn * a.x + dfix * x.x + b.x, 0.f);
  o.y = fmaxf(dn * a.y + dfix * x.y + b.y, 0.f);
  o.z = fmaxf(dn * a.z + dfix * x.z + b.z, 0.f);
  o.w = fmaxf(dn * a.w + dfix * x.w + b.w, 0.f);
  *(float4*)(out + local) = o;
}

template <int PRENORM, int SPLITOUT>
__global__ __launch_bounds__(256) void k_ep_prop(
    const float* __restrict__ part, const float* __restrict__ xw,
    const float* __restrict__ dvec, const float* __restrict__ diag,
    const float* __restrict__ bias, float* __restrict__ out,
    unsigned short* __restrict__ oh, unsigned short* __restrict__ ol) {
  int idx = blockIdx.x * 256 + threadIdx.x;
  size_t i = (size_t)idx * 4;
  int row = (int)(i >> 8), c = (int)(i & 255);
  float4 a = make_float4(0.f, 0.f, 0.f, 0.f);
#pragma unroll
  for (int kb = 0; kb < 8; ++kb) {
    float4 p = *(const float4*)(part + (size_t)kb * M1c + i);
    a.x += p.x; a.y += p.y; a.z += p.z; a.w += p.w;
  }
  float4 x = *(const float4*)(xw + i);
  float4 b = *(const float4*)(bias + c);
  float dn = dvec[row], dfix = (1.f - diag[row]) * dn * dn;
  float s = PRENORM ? 1.f : dn;
  float4 o;
  o.x = fmaxf(s * a.x + dfix * x.x + b.x, 0.f);
  o.y = fmaxf(s * a.y + dfix * x.y + b.y, 0.f);
  o.z = fmaxf(s * a.z + dfix * x.z + b.z, 0.f);
  o.w = fmaxf(s * a.w + dfix * x.w + b.w, 0.f);
  *(float4*)(out + i) = o;
  if constexpr (SPLITOUT) {
    ushort4 hv, lv;
    split1(o.x, ((unsigned short*)&hv)[0], ((unsigned short*)&lv)[0]);
    split1(o.y, ((unsigned short*)&hv)[1], ((unsigned short*)&lv)[1]);
    split1(o.z, ((unsigned short*)&hv)[2], ((unsigned short*)&lv)[2]);
    split1(o.w, ((unsigned short*)&hv)[3], ((unsigned short*)&lv)[3]);
    *(ushort4*)(oh + i) = hv;
    *(ushort4*)(ol + i) = lv;
  }
}

__global__ __launch_bounds__(256) void k_red2(const float* __restrict__ part,
                                              float* __restrict__ out) {
  int idx = blockIdx.x * 256 + threadIdx.x;
  size_t i = (size_t)idx * 4;
  float4 p0 = *(const float4*)(part + i);
  float4 p1 = *(const float4*)(part + M1c + i);
  float4 o;
  o.x = p0.x + p1.x; o.y = p0.y + p1.y; o.z = p0.z + p1.z; o.w = p0.w + p1.w;
  *(float4*)(out + i) = o;
}

__global__ __launch_bounds__(256) void k_ep_heads(
    const float* __restrict__ part, const float* __restrict__ b0,
    const float* __restrict__ b1, const float* __restrict__ b2,
    const float* __restrict__ b3, float* __restrict__ o0, float* __restrict__ o1,
    float* __restrict__ o2, float* __restrict__ o3) {
  int idx = blockIdx.x * 256 + threadIdx.x;
  size_t i = (size_t)idx * 4;
  int row = (int)(i >> 8), c = (int)(i & 255);
  int head = c >> 6, cc = c & 63;
  float4 a = make_float4(0.f, 0.f, 0.f, 0.f);
#pragma unroll
  for (int kb = 0; kb < 4; ++kb) {
    float4 p = *(const float4*)(part + (size_t)kb * M1c + i);
    a.x += p.x; a.y += p.y; a.z += p.z; a.w += p.w;
  }
  const float* bias = (head == 0) ? b0 : (head == 1) ? b1 : (head == 2) ? b2 : b3;
  float* outp = (head == 0) ? o0 : (head == 1) ? o1 : (head == 2) ? o2 : o3;
  float4 b = *(const float4*)(bias + cc);
  float4 o;
  o.x = fmaxf(a.x + b.x, 0.f); o.y = fmaxf(a.y + b.y, 0.f);
  o.z = fmaxf(a.z + b.z, 0.f); o.w = fmaxf(a.w + b.w, 0.f);
  if (head & 1) {
    o.x = 1.f / (1.f + expf(-o.x)); o.y = 1.f / (1.f + expf(-o.y));
    o.z = 1.f / (1.f + expf(-o.z)); o.w = 1.f / (1.f + expf(-o.w));
  }
  *(float4*)(outp + (size_t)row * 64 + cc) = o;
}

__global__ void k_beta(const float* __restrict__ s, float* __restrict__ bb) {
  if (threadIdx.x == 0 && blockIdx.x == 0) {
    const float inv = 1.f / 4096.f;
    float c0 = s[0] * inv, c1 = s[1] * inv;
    float m = fmaxf(c0, c1);
    float e0 = expf(c0 - m), e1 = expf(c1 - m);
    float is = 1.f / (e0 + e1);
    bb[0] = e0 * is; bb[1] = e1 * is;
    float d0 = s[2] * inv, d1 = s[3] * inv, d2 = s[4] * inv, d3 = s[5] * inv;
    float md = fmaxf(fmaxf(d0, d1), fmaxf(d2, d3));
    float f0 = expf(d0 - md), f1 = expf(d1 - md), f2 = expf(d2 - md), f3 = expf(d3 - md);
    float id = 1.f / (f0 + f1 + f2 + f3);
    bb[2] = f0 * id; bb[3] = f1 * id; bb[4] = f2 * id; bb[5] = f3 * id;
  }
}

__global__ __launch_bounds__(256) void k_agg(
    const float* __restrict__ cr0, const float* __restrict__ cr1,
    const float* __restrict__ dr0, const float* __restrict__ dr1,
    const float* __restrict__ bb, float* __restrict__ cagg, float* __restrict__ dagg) {
  size_t i = ((size_t)blockIdx.x * 256 + threadIdx.x) * 4;
  float4 a = *(const float4*)(cr0 + i);
  float4 b = *(const float4*)(cr1 + i);
  float4 c = *(const float4*)(dr0 + i);
  float4 d = *(const float4*)(dr1 + i);
  float bc0 = bb[0], bc1 = bb[1], bd0 = bb[2], bd1 = bb[3], bd2 = bb[4], bd3 = bb[5];
  float4 ca, da;
  ca.x = bc0 * a.x + bc1 * b.x; ca.y = bc0 * a.y + bc1 * b.y;
  ca.z = bc0 * a.z + bc1 * b.z; ca.w = bc0 * a.w + bc1 * b.w;
  da.x = bd0 * a.x + bd1 * b.x + bd2 * c.x + bd3 * d.x;
  da.y = bd0 * a.y + bd1 * b.y + bd2 * c.y + bd3 * d.y;
  da.z = bd0 * a.z + bd1 * b.z + bd2 * c.z + bd3 * d.z;
  da.w = bd0 * a.w + bd1 * b.w + bd2 * c.w + bd3 * d.w;
  *(float4*)(cagg + i) = ca;
  *(float4*)(dagg + i) = da;
}

__global__ __launch_bounds__(256) void k_gather(
    const int* __restrict__ xs, const float* __restrict__ U1, const float* __restrict__ U2,
    const float* __restrict__ V1, const float* __restrict__ V2, float* __restrict__ out) {
  int b = blockIdx.x, j = threadIdx.x;
  int row = xs[b];
  size_t r = (size_t)row * 256;
  out[(size_t)b * 512 + j] = 0.5f * (U1[r + j] + U2[r + j]);
  out[(size_t)b * 512 + 256 + j] = 0.5f * (V1[r + j] + V2[r + j]);
}

// ---------------------------------------------------------------------------
extern "C" void kernel_launch(void* const* d_in, const int* in_sizes, int n_in,
                              void* d_out, int out_size, void* d_ws, size_t ws_size,
                              hipStream_t stream) {
  const float* c0adj = (const float*)d_in[0];
  const float* c1adj = (const float*)d_in[1];
  const float* d0adj = (const float*)d_in[2];
  const float* d1adj = (const float*)d_in[3];
  const float* feats = (const float*)d_in[4];
  const float* W_comm = (const float*)d_in[5];
  const float* b_comm = (const float*)d_in[6];
  const float* W_diff = (const float*)d_in[7];
  const float* b_diff = (const float*)d_in[8];
  const float* W_catt1 = (const float*)d_in[9];
  const float* b_catt1 = (const float*)d_in[10];
  const float* w_catt2 = (const float*)d_in[11];
  const float* W_datt1 = (const float*)d_in[12];
  const float* b_datt1 = (const float*)d_in[13];
  const float* w_datt2 = (const float*)d_in[14];
  const float* W_mu_c = (const float*)d_in[15];
  const float* b_mu_c = (const float*)d_in[16];
  const float* W_var_c = (const float*)d_in[17];
  const float* b_var_c = (const float*)d_in[18];
  const float* W_mu_d = (const float*)d_in[19];
  const float* b_mu_d = (const float*)d_in[20];
  const float* W_var_d = (const float*)d_in[21];
  const float* b_var_d = (const float*)d_in[22];
  const float* W_z1_1 = (const float*)d_in[23];
  const float* b_z1_1 = (const float*)d_in[24];
  const float* W_z1_2 = (const float*)d_in[25];
  const float* b_z1_2 = (const float*)d_in[26];
  const float* wb_z1 = (const float*)d_in[27];
  const float* Wt_c = (const float*)d_in[28];
  const float* Wt_d = (const float*)d_in[29];
  const float* W_z2_1 = (const float*)d_in[30];
  const float* b_z2_1 = (const float*)d_in[31];
  const float* W_z2_2 = (const float*)d_in[32];
  const float* b_z2_2 = (const float*)d_in[33];
  const float* wb_z2 = (const float*)d_in[34];
  const int* xs = (const int*)d_in[35];

  float* out = (float*)d_out;
  float* out_muc = out + 65536;
  float* out_varc = out + 327680;
  float* out_mud = out + 589824;
  float* out_vard = out + 851968;

  float* ws = (float*)d_ws;
  const size_t M1 = M1c;
  float* xw_comm = ws + 0 * M1;
  float* xw_diff = ws + 1 * M1;
  float* xw_z1 = ws + 2 * M1;
  float* xw_z2 = ws + 3 * M1;
  float* cr0 = ws + 4 * M1;
  float* cr1 = ws + 5 * M1;
  float* dr0 = ws + 6 * M1;
  float* dr1 = ws + 7 * M1;
  float* u1 = ws + 8 * M1;
  float* u2 = ws + 9 * M1;
  float* v1 = ws + 10 * M1;
  float* v2 = ws + 11 * M1;
  float* uw = ws + 12 * M1;
  float* cagg = ws + 13 * M1;
  float* dagg = ws + 14 * M1;
  float* accb4 = ws + 15 * M1;  // slots 15-18 (small partials: uw/heads)
  unsigned short* B4h[4];
  unsigned short* B4l[4];
  for (int t = 0; t < 4; ++t) {  // slots 19-22 (B pairs, 1 slot each)
    B4h[t] = (unsigned short*)(ws + (19 + t) * M1);
    B4l[t] = B4h[t] + (size_t)256 * 4096;
  }
  unsigned short* A1h = (unsigned short*)(ws + 23 * M1);  // slots 23-30
  unsigned short* A1l = (unsigned short*)(ws + 31 * M1);  // slots 31-38
  unsigned short* Cch = (unsigned short*)(ws + 23 * M1);  // overlay dead A1h
  unsigned short* Ccl = (unsigned short*)(ws + 25 * M1);
  unsigned short* Cdh = (unsigned short*)(ws + 27 * M1);
  unsigned short* Cdl = (unsigned short*)(ws + 29 * M1);
  float* partZ2 = ws + 31 * M1;  // 8 slots (dead A1l, during z2)
  float* tmpb = ws + 39 * M1;    // 16 slots
  float* part16 = ws + 39 * M1;  // prop partials (pre-cos2)
  float* partZ1 = ws + 39 * M1;  // z1 partials (pre-cos2)
  unsigned short* A2h = (unsigned short*)(ws + 39 * M1);  // cos2 output overlays
  unsigned short* A2l = (unsigned short*)(ws + 47 * M1);
  unsigned short* u1h = (unsigned short*)(ws + 55 * M1);
  unsigned short* u1l = u1h + (size_t)4096 * 256;
  unsigned short* v1h = (unsigned short*)(ws + 56 * M1);
  unsigned short* v1l = v1h + (size_t)4096 * 256;
  float* vecs = ws + 57 * M1;
#define VV(i) (vecs + (size_t)(i) * 4096)
  float* rs_c0 = VV(0); float* rs_c1 = VV(1); float* rs_d0 = VV(2); float* rs_d1 = VV(3);
  float* dg_c0 = VV(4); float* dg_c1 = VV(5); float* dg_d0 = VV(6); float* dg_d1 = VV(7);
  float* cs_tmp = VV(8); float* rs_A2 = VV(9);
  float* d_c0 = VV(10); float* d_c1 = VV(11); float* d_dd0 = VV(12); float* d_dd1 = VV(13);
  float* d_A1 = VV(14); float* d_A2 = VV(15);
  float* gP_dd0 = VV(16); float* gP_dd1 = VV(17); float* gP_A1 = VV(18); float* gP_A2 = VV(19);
  float* satt = VV(20);
  float* beta = satt + 8;

  hipMemsetAsync(cs_tmp, 0, 2 * 4096 * sizeof(float), stream);  // cs_tmp + rs_A2
  hipMemsetAsync(satt, 0, 64, stream);

  // adjacency pass
  k_rowsums<<<1024, 256, 0, stream>>>(c0adj, c1adj, d0adj, d1adj, wb_z1, tmpb,
                                      rs_c0, rs_c1, rs_d0, rs_d1, dg_c0, dg_c1, dg_d0, dg_d1);
  k_colsum<<<dim3(4, 32), 256, 0, stream>>>(tmpb, cs_tmp);
  k_fin<<<16, 256, 0, stream>>>(rs_c0, rs_c1, rs_d0, rs_d1, dg_c0, dg_c1, dg_d0, dg_d1,
                                cs_tmp, wb_z1, d_c0, d_c1, d_dd0, d_dd1, d_A1,
                                gP_dd0, gP_dd1, gP_A1);
  k_addTn<<<dim3(64, 64), 256, 0, stream>>>(tmpb, d_A1, A1h, A1l);

  // fused feats @ W: K=512, KS=2, Kc=256 -> 8 partials -> xw
  k_prepB<<<dim3(8, 4), 256, 0, stream>>>(W_comm, nullptr, B4h[0], B4l[0], 512, 256);
  k_prepB<<<dim3(8, 4), 256, 0, stream>>>(W_diff, nullptr, B4h[1], B4l[1], 512, 256);
  k_prepB<<<dim3(8, 4), 256, 0, stream>>>(W_z1_1, nullptr, B4h[2], B4l[2], 512, 256);
  k_prepB<<<dim3(8, 4), 256, 0, stream>>>(W_z2_1, nullptr, B4h[3], B4l[3], 512, 256);
  k_prop4S<<<512, 256, 0, stream>>>(
      feats, feats, feats, feats, feats, feats, 0,
      nullptr, nullptr, nullptr, nullptr,
      B4h[0], B4l[0], B4h[1], B4l[1], B4h[2], B4l[2], B4h[3], B4l[3],
      part16, 512, 256, 2);
  k_redxw<<<4096, 256, 0, stream>>>(part16, xw_comm, xw_diff, xw_z1, xw_z2);

  // fused adjacency props: KS=2 (Kc=2048), shared B panels, k-scale at A-staging
  k_prepB<<<dim3(64, 4), 256, 0, stream>>>(xw_comm, nullptr, B4h[0], B4l[0], 4096, 256);
  k_prepB<<<dim3(64, 4), 256, 0, stream>>>(xw_diff, nullptr, B4h[1], B4l[1], 4096, 256);
  k_prop4S<<<512, 256, 0, stream>>>(
      c0adj, c1adj, d0adj, d1adj, c0adj, c1adj, 0xC,
      d_c0, d_c1, d_dd0, d_dd1,
      B4h[0], B4l[0], B4h[0], B4l[0], B4h[1], B4l[1], B4h[1], B4l[1],
      part16, 4096, 2048, 2);
  k_ep_prop4<<<4096, 256, 0, stream>>>(part16, xw_comm, xw_diff, d_c0, d_c1, d_dd0, d_dd1,
                                       dg_c0, dg_c1, gP_dd0, gP_dd1, b_comm, b_diff,
                                       cr0, cr1, dr0, dr1);

  unsigned short* Bth = B4h[0];
  unsigned short* BtlL = Bth + (size_t)256 * 4096;
  unsigned short* BthS = Bth;
  unsigned short* BtlS = Bth + (size_t)256 * 256;

  // ---- z1 branch (before cos2; uses A1, partials in pre-A2 region) ----
  k_prepB<<<dim3(64, 4), 256, 0, stream>>>(xw_z1, nullptr, Bth, BtlL, 4096, 256);
  k_gemmS<<<1024, 256, 0, stream>>>(A1h, A1l, Bth, BtlL, partZ1, 4096, 512);
  k_ep_prop<1, 1><<<1024, 256, 0, stream>>>(partZ1, xw_z1, d_A1, gP_A1, b_z1_1, u1, u1h, u1l);
  k_prepB<<<dim3(4, 4), 256, 0, stream>>>(W_z1_2, nullptr, BthS, BtlS, 256, 256);
  k_gemmS<<<256, 256, 0, stream>>>(u1h, u1l, BthS, BtlS, accb4, 256, 128);
  k_red2<<<1024, 256, 0, stream>>>(accb4, uw);
  k_prepB<<<dim3(64, 4), 256, 0, stream>>>(uw, nullptr, Bth, BtlL, 4096, 256);
  k_gemmS<<<1024, 256, 0, stream>>>(A1h, A1l, Bth, BtlL, partZ1, 4096, 512);
  k_ep_prop<1, 0><<<1024, 256, 0, stream>>>(partZ1, uw, d_A1, gP_A1, b_z1_2, u2, nullptr, nullptr);

  // attention scoring via MFMA (fused tanh·w2 reduce), then beta + agg
  {
    unsigned short* Wch = B4h[1];
    unsigned short* Wcl = Wch + (size_t)128 * 256;
    unsigned short* Wdh = B4h[2];
    unsigned short* Wdl = Wdh + (size_t)128 * 256;
    k_prepB<<<dim3(4, 2), 256, 0, stream>>>(W_catt1, nullptr, Wch, Wcl, 256, 128);
    k_prepB<<<dim3(4, 2), 256, 0, stream>>>(W_datt1, nullptr, Wdh, Wdl, 256, 128);
    k_attG<<<dim3(64, 6), 256, 0, stream>>>(cr0, cr1, dr0, dr1, Wch, Wcl, Wdh, Wdl,
                                            b_catt1, w_catt2, b_datt1, w_datt2, satt);
  }
  k_beta<<<1, 64, 0, stream>>>(satt, beta);
  k_agg<<<1024, 256, 0, stream>>>(cr0, cr1, dr0, dr1, beta, cagg, dagg);

  // heads: dual-A GEMM (KS=4, partials in accb4)
  {
    unsigned short* Hh = B4h[0];
    unsigned short* Hl = Hh + (size_t)256 * 256;
    k_prepB<<<dim3(4, 1), 256, 0, stream>>>(W_mu_c, nullptr, Hh + 0 * 64 * 256, Hl + 0 * 64 * 256, 256, 64);
    k_prepB<<<dim3(4, 1), 256, 0, stream>>>(W_var_c, nullptr, Hh + 1 * 64 * 256, Hl + 1 * 64 * 256, 256, 64);
    k_prepB<<<dim3(4, 1), 256, 0, stream>>>(W_mu_d, nullptr, Hh + 2 * 64 * 256, Hl + 2 * 64 * 256, 256, 64);
    k_prepB<<<dim3(4, 1), 256, 0, stream>>>(W_var_d, nullptr, Hh + 3 * 64 * 256, Hl + 3 * 64 * 256, 256, 64);
    k_gemmH<<<dim3(4, 64), 256, 0, stream>>>(cagg, dagg, Hh, Hl, accb4, 256, 64);
    k_ep_heads<<<1024, 256, 0, stream>>>(accb4, b_mu_c, b_var_c, b_mu_d, b_var_d,
                                         out_muc, out_varc, out_mud, out_vard);
  }

  // cosine contexts -> split pairs (dead A1h region), one dispatch
  k_cn2<<<32768, 256, 0, stream>>>(out_muc, Wt_c, out_mud, Wt_d, Cch, Ccl, Cdh, Cdl);

  // A2 (symmetric dual-Gram, compact 528-block upper-tri grid, XCD swizzle)
  k_cos2<<<528, 256, 0, stream>>>(Cch, Ccl, Cdh, Cdl, wb_z2, rs_A2, gP_A2, A2h, A2l);
  k_dA2<<<16, 256, 0, stream>>>(rs_A2, gP_A2, d_A2);

  // ---- z2 branch (partials in dead A1l region) ----
  k_prepB<<<dim3(64, 4), 256, 0, stream>>>(xw_z2, d_A2, Bth, BtlL, 4096, 256);
  k_gemmS<<<1024, 256, 0, stream>>>(A2h, A2l, Bth, BtlL, partZ2, 4096, 512);
  k_ep_prop<0, 1><<<1024, 256, 0, stream>>>(partZ2, xw_z2, d_A2, gP_A2, b_z2_1, v1, v1h, v1l);
  k_prepB<<<dim3(4, 4), 256, 0, stream>>>(W_z2_2, nullptr, BthS, BtlS, 256, 256);
  k_gemmS<<<256, 256, 0, stream>>>(v1h, v1l, BthS, BtlS, accb4, 256, 128);
  k_red2<<<1024, 256, 0, stream>>>(accb4, uw);
  k_prepB<<<dim3(64, 4), 256, 0, stream>>>(uw, d_A2, Bth, BtlL, 4096, 256);
  k_gemmS<<<1024, 256, 0, stream>>>(A2h, A2l, Bth, BtlL, partZ2, 4096, 512);
  k_ep_prop<0, 0><<<1024, 256, 0, stream>>>(partZ2, uw, d_A2, gP_A2, b_z2_2, v2, nullptr, nullptr);

  // h[xs]
  k_gather<<<128, 256, 0, stream>>>(xs, u1, u2, v1, v2, out);
}

// Round 20
// 1004.924 us; speedup vs baseline: 1.0907x; 1.0907x over previous
//
#include <hip/hip_runtime.h>
#include <math.h>

// N=4096, F_IN=512, Z=256, H=256, E=64, ATT=128, NPER=16, B=128
using f32x4 = __attribute__((ext_vector_type(4))) float;
using bf16x8 = __attribute__((ext_vector_type(8))) short;
#define MFMA16 __builtin_amdgcn_mfma_f32_16x16x32_bf16
static constexpr size_t M1c = 1048576;

__device__ __forceinline__ float wave_reduce_sum(float v) {
#pragma unroll
  for (int off = 32; off > 0; off >>= 1) v += __shfl_down(v, off);
  return v;
}

__device__ __forceinline__ unsigned short f2bf_rne(float x) {
  unsigned int u = __float_as_uint(x);
  unsigned int r = u + 0x7FFFu + ((u >> 16) & 1u);
  return (unsigned short)(r >> 16);
}
__device__ __forceinline__ void split1(float x, unsigned short& h, unsigned short& l) {
  unsigned int u = __float_as_uint(x);
  h = (unsigned short)(u >> 16);
  float rem = x - __uint_as_float(u & 0xFFFF0000u);
  l = f2bf_rne(rem);
}
__device__ __forceinline__ void split8(const float* f, bf16x8& h, bf16x8& l) {
#pragma unroll
  for (int i = 0; i < 8; ++i) {
    unsigned short hh, ll;
    split1(f[i], hh, ll);
    h[i] = (short)hh;
    l[i] = (short)ll;
  }
}

// ---------------------------------------------------------------------------
// Adjacency pass (vectorized float4); 1 row per wave, grid 1024
// ---------------------------------------------------------------------------
__global__ __launch_bounds__(256) void k_rowsums(
    const float* __restrict__ c0, const float* __restrict__ c1,
    const float* __restrict__ d0, const float* __restrict__ d1,
    const float* __restrict__ wb, float* __restrict__ tmp,
    float* __restrict__ rs_c0, float* __restrict__ rs_c1,
    float* __restrict__ rs_d0, float* __restrict__ rs_d1,
    float* __restrict__ dg_c0, float* __restrict__ dg_c1,
    float* __restrict__ dg_d0, float* __restrict__ dg_d1) {
  int wave = threadIdx.x >> 6, lane = threadIdx.x & 63;
  float hw0 = 0.5f * wb[0], hw1 = 0.5f * wb[1];
  int row = blockIdx.x * 4 + wave;
  const float4* pc0 = (const float4*)(c0 + (size_t)row * 4096);
  const float4* pc1 = (const float4*)(c1 + (size_t)row * 4096);
  const float4* pd0 = (const float4*)(d0 + (size_t)row * 4096);
  const float4* pd1 = (const float4*)(d1 + (size_t)row * 4096);
  float4* pt = (float4*)(tmp + (size_t)row * 4096);
  float s0 = 0.f, s1 = 0.f, s2 = 0.f, s3 = 0.f;
  int dq = row >> 2, dcomp = row & 3;
  for (int ct = 0; ct < 16; ++ct) {
    int c4 = ct * 64 + lane;
    float4 a = pc0[c4], b = pc1[c4], e = pd0[c4], f = pd1[c4];
    s0 += a.x + a.y + a.z + a.w;
    s1 += b.x + b.y + b.z + b.w;
    s2 += e.x + e.y + e.z + e.w;
    s3 += f.x + f.y + f.z + f.w;
    float4 t4;
    t4.x = hw0 * (a.x + b.x) + hw1 * (e.x + f.x);
    t4.y = hw0 * (a.y + b.y) + hw1 * (e.y + f.y);
    t4.z = hw0 * (a.z + b.z) + hw1 * (e.z + f.z);
    t4.w = hw0 * (a.w + b.w) + hw1 * (e.w + f.w);
    pt[c4] = t4;
    if (c4 == dq) {
      dg_c0[row] = dcomp == 0 ? a.x : dcomp == 1 ? a.y : dcomp == 2 ? a.z : a.w;
      dg_c1[row] = dcomp == 0 ? b.x : dcomp == 1 ? b.y : dcomp == 2 ? b.z : b.w;
      dg_d0[row] = dcomp == 0 ? e.x : dcomp == 1 ? e.y : dcomp == 2 ? e.z : e.w;
      dg_d1[row] = dcomp == 0 ? f.x : dcomp == 1 ? f.y : dcomp == 2 ? f.z : f.w;
    }
  }
  s0 = wave_reduce_sum(s0); s1 = wave_reduce_sum(s1);
  s2 = wave_reduce_sum(s2); s3 = wave_reduce_sum(s3);
  if (lane == 0) { rs_c0[row] = s0; rs_c1[row] = s1; rs_d0[row] = s2; rs_d1[row] = s3; }
}

// Column sums, vectorized: grid (4, 32); c4 = float4 column index
__global__ __launch_bounds__(256) void k_colsum(const float* __restrict__ T,
                                                float* __restrict__ cs) {
  int c4 = blockIdx.x * 256 + threadIdx.x;
  int r0 = blockIdx.y * 128;
  const float4* T4 = (const float4*)T;
  float4 a = make_float4(0.f, 0.f, 0.f, 0.f);
  for (int r = r0; r < r0 + 128; ++r) {
    float4 p = T4[(size_t)r * 1024 + c4];
    a.x += p.x; a.y += p.y; a.z += p.z; a.w += p.w;
  }
  atomicAdd(&cs[c4 * 4 + 0], a.x);
  atomicAdd(&cs[c4 * 4 + 1], a.y);
  atomicAdd(&cs[c4 * 4 + 2], a.z);
  atomicAdd(&cs[c4 * 4 + 3], a.w);
}

// A1n = d[row]*d[col]*(tmp + tmp^T) -> split-bf16 pair (float4/ushort4 path)
__global__ __launch_bounds__(256) void k_addTn(const float* __restrict__ T,
                                               const float* __restrict__ dv,
                                               unsigned short* __restrict__ A1h,
                                               unsigned short* __restrict__ A1l) {
  __shared__ float t[64][65];
  int bi = blockIdx.y, bj = blockIdx.x;
  int r = threadIdx.x >> 4;        // 0..15
  int c4 = threadIdx.x & 15;       // float4 col index within 64
#pragma unroll
  for (int rr = 0; rr < 4; ++rr) {
    int row = rr * 16 + r;
    float4 v = *(const float4*)(T + (size_t)(bj * 64 + row) * 4096 + bi * 64 + c4 * 4);
    t[row][c4 * 4 + 0] = v.x; t[row][c4 * 4 + 1] = v.y;
    t[row][c4 * 4 + 2] = v.z; t[row][c4 * 4 + 3] = v.w;
  }
  __syncthreads();
#pragma unroll
  for (int rr = 0; rr < 4; ++rr) {
    int ro = rr * 16 + r;
    int rowg = bi * 64 + ro;
    float dr = dv[rowg];
    size_t idx = (size_t)rowg * 4096 + bj * 64 + c4 * 4;
    float4 a = *(const float4*)(T + idx);
    float f0 = (a.x + t[c4 * 4 + 0][ro]) * dr * dv[bj * 64 + c4 * 4 + 0];
    float f1 = (a.y + t[c4 * 4 + 1][ro]) * dr * dv[bj * 64 + c4 * 4 + 1];
    float f2 = (a.z + t[c4 * 4 + 2][ro]) * dr * dv[bj * 64 + c4 * 4 + 2];
    float f3 = (a.w + t[c4 * 4 + 3][ro]) * dr * dv[bj * 64 + c4 * 4 + 3];
    ushort4 hv, lv;
    split1(f0, ((unsigned short*)&hv)[0], ((unsigned short*)&lv)[0]);
    split1(f1, ((unsigned short*)&hv)[1], ((unsigned short*)&lv)[1]);
    split1(f2, ((unsigned short*)&hv)[2], ((unsigned short*)&lv)[2]);
    split1(f3, ((unsigned short*)&hv)[3], ((unsigned short*)&lv)[3]);
    *(ushort4*)(A1h + idx) = hv;
    *(ushort4*)(A1l + idx) = lv;
  }
}

__global__ __launch_bounds__(256) void k_fin(
    const float* __restrict__ rs_c0, const float* __restrict__ rs_c1,
    const float* __restrict__ rs_d0, const float* __restrict__ rs_d1,
    const float* __restrict__ dg_c0, const float* __restrict__ dg_c1,
    const float* __restrict__ dg_d0, const float* __restrict__ dg_d1,
    const float* __restrict__ cs_tmp, const float* __restrict__ wb,
    float* __restrict__ d_c0, float* __restrict__ d_c1,
    float* __restrict__ d_dd0, float* __restrict__ d_dd1, float* __restrict__ d_A1,
    float* __restrict__ gP_dd0, float* __restrict__ gP_dd1, float* __restrict__ gP_A1) {
  int n = blockIdx.x * 256 + threadIdx.x;
  float rc0 = rs_c0[n], rc1 = rs_c1[n], rd0 = rs_d0[n], rd1 = rs_d1[n];
  float gc0 = dg_c0[n], gc1 = dg_c1[n], gd0 = dg_d0[n], gd1 = dg_d1[n];
  d_c0[n] = rsqrtf(fmaxf(rc0 - gc0 + 1.f, 1.f));
  d_c1[n] = rsqrtf(fmaxf(rc1 - gc1 + 1.f, 1.f));
  float cmr = 0.5f * (rc0 + rc1), cmg = 0.5f * (gc0 + gc1);
  float g0 = gd0 + cmg; gP_dd0[n] = g0;
  d_dd0[n] = rsqrtf(fmaxf(rd0 + cmr - g0 + 1.f, 1.f));
  float g1 = gd1 + cmg; gP_dd1[n] = g1;
  d_dd1[n] = rsqrtf(fmaxf(rd1 + cmr - g1 + 1.f, 1.f));
  float w0 = wb[0], w1 = wb[1];
  float rt = w0 * cmr + w1 * 0.5f * (rd0 + rd1);
  float gt = w0 * cmg + w1 * 0.5f * (gd0 + gd1);
  gP_A1[n] = 2.f * gt;
  d_A1[n] = rsqrtf(fmaxf(rt + cs_tmp[n] - 2.f * gt + 1.f, 1.f));
}

__global__ __launch_bounds__(256) void k_dA2(const float* __restrict__ rs,
                                             const float* __restrict__ gP,
                                             float* __restrict__ dvec) {
  int n = blockIdx.x * 256 + threadIdx.x;
  dvec[n] = rsqrtf(fmaxf(rs[n] - gP[n] + 1.f, 1.f));
}

// cn rows -> split bf16 pair [4096][1024], both contexts in one dispatch
__global__ __launch_bounds__(256) void k_cn2(
    const float* __restrict__ mu_c, const float* __restrict__ Wt_c,
    const float* __restrict__ mu_d, const float* __restrict__ Wt_d,
    unsigned short* __restrict__ Cch, unsigned short* __restrict__ Ccl,
    unsigned short* __restrict__ Cdh, unsigned short* __restrict__ Cdl) {
  int g = blockIdx.x * 4 + (threadIdx.x >> 6);
  int lane = threadIdx.x & 63;
  bool dsel = g >= 65536;
  int gg = dsel ? g - 65536 : g;
  const float* mu = dsel ? mu_d : mu_c;
  const float* Wt = dsel ? Wt_d : Wt_c;
  unsigned short* Oh = dsel ? Cdh : Cch;
  unsigned short* Ol = dsel ? Cdl : Ccl;
  int n = gg >> 4, p = gg & 15;
  float v = mu[(size_t)n * 64 + lane] * Wt[p * 64 + lane];
  float ss = v * v;
#pragma unroll
  for (int off = 32; off > 0; off >>= 1) ss += __shfl_xor(ss, off);
  float nrm = fmaxf(sqrtf(ss), 1e-12f);
  float r = v / nrm;
  unsigned short h, l;
  split1(r, h, l);
  size_t o = (size_t)n * 1024 + p * 64 + lane;
  Oh[o] = h; Ol[o] = l;
}

// ---------------------------------------------------------------------------
// prepB: X [K][C] fp32 (optional per-k scale) -> Bt hi/lo bf16 [C][K]
// ---------------------------------------------------------------------------
__global__ __launch_bounds__(256) void k_prepB(const float* __restrict__ X,
                                               const float* __restrict__ scale,
                                               unsigned short* __restrict__ Bh,
                                               unsigned short* __restrict__ Bl,
                                               int K, int C) {
  __shared__ float t[64][65];
  int kb = blockIdx.x * 64, cb = blockIdx.y * 64;
  int lane = threadIdx.x & 63, w = threadIdx.x >> 6;
  for (int i = 0; i < 16; ++i) {
    int kk = w * 16 + i;
    float s = scale ? scale[kb + kk] : 1.f;
    t[kk][lane] = X[(size_t)(kb + kk) * C + cb + lane] * s;
  }
  __syncthreads();
  for (int i = 0; i < 16; ++i) {
    int cc = w * 16 + i;
    float v = t[lane][cc];
    unsigned short h, l;
    split1(v, h, l);
    size_t o = (size_t)(cb + cc) * K + kb + lane;
    Bh[o] = h; Bl[o] = l;
  }
}

// ---------------------------------------------------------------------------
// Fused 4-segment GEMM, BM=64 x BN=256, BK=64 pair-step pipeline, partials.
// 1-D grid with XCD-aware bijective swizzle: gridDim.x = 4*KS*64 (%8==0).
// ---------------------------------------------------------------------------
__global__ __launch_bounds__(256) void k_prop4S(
    const float* __restrict__ As0, const float* __restrict__ As1,
    const float* __restrict__ As2, const float* __restrict__ As3,
    const float* __restrict__ Ax0, const float* __restrict__ Ax1, int cmask,
    const float* __restrict__ dsc0, const float* __restrict__ dsc1,
    const float* __restrict__ dsc2, const float* __restrict__ dsc3,
    const unsigned short* __restrict__ B0h, const unsigned short* __restrict__ B0l,
    const unsigned short* __restrict__ B1h, const unsigned short* __restrict__ B1l,
    const unsigned short* __restrict__ B2h, const unsigned short* __restrict__ B2l,
    const unsigned short* __restrict__ B3h, const unsigned short* __restrict__ B3l,
    float* __restrict__ part, int K, int Kc, int KS) {
  int d = blockIdx.x;
  int q = gridDim.x >> 3;
  int lin = (d & 7) * q + (d >> 3);
  int mblk = lin & 63;
  int sk = lin >> 6;
  int seg = sk / KS, kb = sk % KS;
  const float* A = seg == 0 ? As0 : seg == 1 ? As1 : seg == 2 ? As2 : As3;
  const unsigned short* Bh = seg == 0 ? B0h : seg == 1 ? B1h : seg == 2 ? B2h : B3h;
  const unsigned short* Bl = seg == 0 ? B0l : seg == 1 ? B1l : seg == 2 ? B2l : B3l;
  const float* dsc = seg == 0 ? dsc0 : seg == 1 ? dsc1 : seg == 2 ? dsc2 : dsc3;
  const bool usecm = (cmask >> seg) & 1;
  const bool usesc = dsc != nullptr;
  __shared__ unsigned char sm[2][2][8192];  // [pairbuf][half][64 rows x 128B]
  const int tid = threadIdx.x;
  const int m0 = mblk * 64, k0 = kb * Kc;
  const int w = tid >> 6, lane = tid & 63;
  const int lr = lane & 15, lk = (lane >> 4) * 8, n0w = w * 64;
  const int srow = tid >> 2, skp = (tid & 3) * 8;
  const int swz = (srow & 7) << 4;
  const int offh = (srow * 128 + skp * 2) ^ swz;
  const int offl = (srow * 128 + 64 + skp * 2) ^ swz;
  const size_t rowoff = (size_t)(m0 + srow) * K + k0 + skp;
  const float* arow = A + rowoff;
  const float* xrow0 = Ax0 + rowoff;
  const float* xrow1 = Ax1 + rowoff;
  const float* scrow = usesc ? (dsc + k0 + skp) : nullptr;

  float4 xa0, xa1, xb0, xb1;
  float4 ya0, ya1, yb0, yb1;
  float4 za0, za1, zb0, zb1;
  float4 sa0, sa1, sb0, sb1;
  auto ldPair = [&](int kk) {
    xa0 = *(const float4*)(arow + kk);
    xa1 = *(const float4*)(arow + kk + 4);
    xb0 = *(const float4*)(arow + kk + 32);
    xb1 = *(const float4*)(arow + kk + 36);
    if (usecm) {
      ya0 = *(const float4*)(xrow0 + kk);
      ya1 = *(const float4*)(xrow0 + kk + 4);
      yb0 = *(const float4*)(xrow0 + kk + 32);
      yb1 = *(const float4*)(xrow0 + kk + 36);
      za0 = *(const float4*)(xrow1 + kk);
      za1 = *(const float4*)(xrow1 + kk + 4);
      zb0 = *(const float4*)(xrow1 + kk + 32);
      zb1 = *(const float4*)(xrow1 + kk + 36);
    }
    if (usesc) {
      sa0 = *(const float4*)(scrow + kk);
      sa1 = *(const float4*)(scrow + kk + 4);
      sb0 = *(const float4*)(scrow + kk + 32);
      sb1 = *(const float4*)(scrow + kk + 36);
    }
  };
  auto wrPair = [&](int pb) {
    {
      float f[8] = {xa0.x, xa0.y, xa0.z, xa0.w, xa1.x, xa1.y, xa1.z, xa1.w};
      if (usecm) {
        f[0] += 0.5f * (ya0.x + za0.x); f[1] += 0.5f * (ya0.y + za0.y);
        f[2] += 0.5f * (ya0.z + za0.z); f[3] += 0.5f * (ya0.w + za0.w);
        f[4] += 0.5f * (ya1.x + za1.x); f[5] += 0.5f * (ya1.y + za1.y);
        f[6] += 0.5f * (ya1.z + za1.z); f[7] += 0.5f * (ya1.w + za1.w);
      }
      if (usesc) {
        f[0] *= sa0.x; f[1] *= sa0.y; f[2] *= sa0.z; f[3] *= sa0.w;
        f[4] *= sa1.x; f[5] *= sa1.y; f[6] *= sa1.z; f[7] *= sa1.w;
      }
      bf16x8 hh, ll;
      split8(f, hh, ll);
      *(bf16x8*)(&sm[pb][0][0] + offh) = hh;
      *(bf16x8*)(&sm[pb][0][0] + offl) = ll;
    }
    {
      float f[8] = {xb0.x, xb0.y, xb0.z, xb0.w, xb1.x, xb1.y, xb1.z, xb1.w};
      if (usecm) {
        f[0] += 0.5f * (yb0.x + zb0.x); f[1] += 0.5f * (yb0.y + zb0.y);
        f[2] += 0.5f * (yb0.z + zb0.z); f[3] += 0.5f * (yb0.w + zb0.w);
        f[4] += 0.5f * (yb1.x + zb1.x); f[5] += 0.5f * (yb1.y + zb1.y);
        f[6] += 0.5f * (yb1.z + zb1.z); f[7] += 0.5f * (yb1.w + zb1.w);
      }
      if (usesc) {
        f[0] *= sb0.x; f[1] *= sb0.y; f[2] *= sb0.z; f[3] *= sb0.w;
        f[4] *= sb1.x; f[5] *= sb1.y; f[6] *= sb1.z; f[7] *= sb1.w;
      }
      bf16x8 hh, ll;
      split8(f, hh, ll);
      *(bf16x8*)(&sm[pb][1][0] + offh) = hh;
      *(bf16x8*)(&sm[pb][1][0] + offl) = ll;
    }
  };

  f32x4 acc[4][4] = {};
  auto comp = [&](int pb, int half, int kkg) {
    const unsigned char* base = &sm[pb][half][0];
    bf16x8 ah[4], al[4];
#pragma unroll
    for (int i = 0; i < 4; ++i) {
      int row = i * 16 + lr, sz = (row & 7) << 4;
      ah[i] = *(const bf16x8*)(base + ((row * 128 + lk * 2) ^ sz));
      al[i] = *(const bf16x8*)(base + ((row * 128 + 64 + lk * 2) ^ sz));
    }
#pragma unroll
    for (int j = 0; j < 4; ++j) {
      int col = n0w + j * 16 + lr;
      size_t bo = (size_t)col * K + kkg;
      bf16x8 bh = *(const bf16x8*)(Bh + bo);
      bf16x8 bl = *(const bf16x8*)(Bl + bo);
#pragma unroll
      for (int i = 0; i < 4; ++i) {
        acc[i][j] = MFMA16(ah[i], bh, acc[i][j], 0, 0, 0);
        acc[i][j] = MFMA16(ah[i], bl, acc[i][j], 0, 0, 0);
        acc[i][j] = MFMA16(al[i], bh, acc[i][j], 0, 0, 0);
      }
    }
  };

  int pairs = Kc / 64;
  ldPair(0);
  wrPair(0);
  __syncthreads();
  for (int p = 0; p < pairs; ++p) {
    if (p + 1 < pairs) ldPair((p + 1) * 64);
    comp(p & 1, 0, k0 + p * 64 + lk);
    comp(p & 1, 1, k0 + p * 64 + 32 + lk);
    if (p + 1 < pairs) wrPair((p + 1) & 1);
    __syncthreads();
  }
  int rr = (lane >> 4) * 4;
  float* Cp = part + (size_t)(seg * KS + kb) * M1c;
#pragma unroll
  for (int i = 0; i < 4; ++i)
#pragma unroll
    for (int j = 0; j < 4; ++j) {
      int col = n0w + j * 16 + lr;
#pragma unroll
      for (int r = 0; r < 4; ++r)
        Cp[(size_t)(m0 + i * 16 + rr + r) * 256 + col] = acc[i][j][r];
    }
}

// ---------------------------------------------------------------------------
// Single planar-pair GEMM, BM=64, BK=64 pair-step, DEPTH-2 prefetch, partials.
// 1-D grid with XCD-aware swizzle: gridDim.x = KS*64 (%8==0).
// ---------------------------------------------------------------------------
__global__ __launch_bounds__(256) void k_gemmS(
    const unsigned short* __restrict__ Ah, const unsigned short* __restrict__ Al,
    const unsigned short* __restrict__ Bth, const unsigned short* __restrict__ Btl,
    float* __restrict__ part, int K, int Kc) {
  int d = blockIdx.x;
  int q = gridDim.x >> 3;
  int lin = (d & 7) * q + (d >> 3);
  int mblk = lin & 63;
  int kb = lin >> 6;
  __shared__ unsigned char sm[2][2][8192];
  const int tid = threadIdx.x;
  const int m0 = mblk * 64, k0 = kb * Kc;
  const int w = tid >> 6, lane = tid & 63;
  const int lr = lane & 15, lk = (lane >> 4) * 8, n0w = w * 64;
  const int srow = tid >> 2, skp = (tid & 3) * 8;
  const int swz = (srow & 7) << 4;
  const int offh = (srow * 128 + skp * 2) ^ swz;
  const int offl = (srow * 128 + 64 + skp * 2) ^ swz;
  const unsigned short* arh = Ah + (size_t)(m0 + srow) * K + k0 + skp;
  const unsigned short* arl = Al + (size_t)(m0 + srow) * K + k0 + skp;

  // two named register sets: even pairs -> r*, odd pairs -> s*
  bf16x8 rha, rla, rhb, rlb;
  bf16x8 sha, sla, shb, slb;
  auto ld0 = [&](int kk) {
    rha = *(const bf16x8*)(arh + kk);
    rla = *(const bf16x8*)(arl + kk);
    rhb = *(const bf16x8*)(arh + kk + 32);
    rlb = *(const bf16x8*)(arl + kk + 32);
  };
  auto ld1 = [&](int kk) {
    sha = *(const bf16x8*)(arh + kk);
    sla = *(const bf16x8*)(arl + kk);
    shb = *(const bf16x8*)(arh + kk + 32);
    slb = *(const bf16x8*)(arl + kk + 32);
  };
  auto wr0 = [&](int pb) {
    *(bf16x8*)(&sm[pb][0][0] + offh) = rha;
    *(bf16x8*)(&sm[pb][0][0] + offl) = rla;
    *(bf16x8*)(&sm[pb][1][0] + offh) = rhb;
    *(bf16x8*)(&sm[pb][1][0] + offl) = rlb;
  };
  auto wr1 = [&](int pb) {
    *(bf16x8*)(&sm[pb][0][0] + offh) = sha;
    *(bf16x8*)(&sm[pb][0][0] + offl) = sla;
    *(bf16x8*)(&sm[pb][1][0] + offh) = shb;
    *(bf16x8*)(&sm[pb][1][0] + offl) = slb;
  };

  f32x4 acc[4][4] = {};
  auto comp = [&](int pb, int half, int kkg) {
    const unsigned char* base = &sm[pb][half][0];
    bf16x8 ah[4], al[4];
#pragma unroll
    for (int i = 0; i < 4; ++i) {
      int row = i * 16 + lr, sz = (row & 7) << 4;
      ah[i] = *(const bf16x8*)(base + ((row * 128 + lk * 2) ^ sz));
      al[i] = *(const bf16x8*)(base + ((row * 128 + 64 + lk * 2) ^ sz));
    }
#pragma unroll
    for (int j = 0; j < 4; ++j) {
      int col = n0w + j * 16 + lr;
      size_t bo = (size_t)col * K + kkg;
      bf16x8 bh = *(const bf16x8*)(Bth + bo);
      bf16x8 bl = *(const bf16x8*)(Btl + bo);
#pragma unroll
      for (int i = 0; i < 4; ++i) {
        acc[i][j] = MFMA16(ah[i], bh, acc[i][j], 0, 0, 0);
        acc[i][j] = MFMA16(ah[i], bl, acc[i][j], 0, 0, 0);
        acc[i][j] = MFMA16(al[i], bh, acc[i][j], 0, 0, 0);
      }
    }
  };

  int pairs = Kc / 64;
  ld0(0);
  wr0(0);
  if (pairs > 1) ld1(64);
  __syncthreads();
  for (int p = 0; p < pairs; ++p) {
    if (p + 2 < pairs) {
      if ((p & 1) == 0) ld0((p + 2) * 64); else ld1((p + 2) * 64);
    }
    comp(p & 1, 0, k0 + p * 64 + lk);
    comp(p & 1, 1, k0 + p * 64 + 32 + lk);
    if (p + 1 < pairs) {
      if (((p + 1) & 1) == 0) wr0((p + 1) & 1); else wr1((p + 1) & 1);
    }
    __syncthreads();
  }
  int rr = (lane >> 4) * 4;
  float* Cp = part + (size_t)kb * M1c;
#pragma unroll
  for (int i = 0; i < 4; ++i)
#pragma unroll
    for (int j = 0; j < 4; ++j) {
      int col = n0w + j * 16 + lr;
#pragma unroll
      for (int r = 0; r < 4; ++r)
        Cp[(size_t)(m0 + i * 16 + rr + r) * 256 + col] = acc[i][j][r];
    }
}

// ---------------------------------------------------------------------------
// Heads GEMM: dual fp32 A (waves 0-1 Aa, 2-3 Ab), BM=64, partial out.
// grid (4, 64), K=256, Kc=64.
// ---------------------------------------------------------------------------
__global__ __launch_bounds__(256) void k_gemmH(
    const float* __restrict__ Aa, const float* __restrict__ Ab,
    const unsigned short* __restrict__ Bth, const unsigned short* __restrict__ Btl,
    float* __restrict__ part, int K, int Kc) {
  __shared__ unsigned char sm[2][2][8192];
  const int tid = threadIdx.x;
  const int m0 = blockIdx.y * 64, k0 = blockIdx.x * Kc;
  const int w = tid >> 6, lane = tid & 63;
  const int lr = lane & 15, lk = (lane >> 4) * 8, n0w = w * 64;
  const int srow = tid >> 2, skp = (tid & 3) * 8;
  const int swz = (srow & 7) << 4;
  const int offh = (srow * 128 + skp * 2) ^ swz;
  const int offl = (srow * 128 + 64 + skp * 2) ^ swz;
  const int slot = w >> 1;

  auto stage = [&](int b, int kk) {
    int kg = k0 + kk + skp;
    const float* p = Aa + (size_t)(m0 + srow) * K + kg;
    float4 x0 = *(const float4*)(p), x1 = *(const float4*)(p + 4);
    float f[8] = {x0.x, x0.y, x0.z, x0.w, x1.x, x1.y, x1.z, x1.w};
    bf16x8 hh, ll;
    split8(f, hh, ll);
    *(bf16x8*)(&sm[b][0][0] + offh) = hh;
    *(bf16x8*)(&sm[b][0][0] + offl) = ll;
    const float* qq = Ab + (size_t)(m0 + srow) * K + kg;
    float4 y0 = *(const float4*)(qq), y1 = *(const float4*)(qq + 4);
    float g[8] = {y0.x, y0.y, y0.z, y0.w, y1.x, y1.y, y1.z, y1.w};
    split8(g, hh, ll);
    *(bf16x8*)(&sm[b][1][0] + offh) = hh;
    *(bf16x8*)(&sm[b][1][0] + offl) = ll;
  };

  f32x4 acc[4][4] = {};
  stage(0, 0);
  __syncthreads();
  int steps = Kc / 32;
  for (int s = 0; s < steps; ++s) {
    if (s + 1 < steps) stage((s + 1) & 1, (s + 1) * 32);
    const unsigned char* base = &sm[s & 1][slot][0];
    bf16x8 ah[4], al[4];
#pragma unroll
    for (int i = 0; i < 4; ++i) {
      int row = i * 16 + lr, sz = (row & 7) << 4;
      ah[i] = *(const bf16x8*)(base + ((row * 128 + lk * 2) ^ sz));
      al[i] = *(const bf16x8*)(base + ((row * 128 + 64 + lk * 2) ^ sz));
    }
    int kkg = k0 + s * 32 + lk;
#pragma unroll
    for (int j = 0; j < 4; ++j) {
      int col = n0w + j * 16 + lr;
      size_t bo = (size_t)col * K + kkg;
      bf16x8 bh = *(const bf16x8*)(Bth + bo);
      bf16x8 bl = *(const bf16x8*)(Btl + bo);
#pragma unroll
      for (int i = 0; i < 4; ++i) {
        acc[i][j] = MFMA16(ah[i], bh, acc[i][j], 0, 0, 0);
        acc[i][j] = MFMA16(ah[i], bl, acc[i][j], 0, 0, 0);
        acc[i][j] = MFMA16(al[i], bh, acc[i][j], 0, 0, 0);
      }
    }
    __syncthreads();
  }
  int rr = (lane >> 4) * 4;
  float* Cp = part + (size_t)blockIdx.x * M1c;
#pragma unroll
  for (int i = 0; i < 4; ++i)
#pragma unroll
    for (int j = 0; j < 4; ++j) {
      int col = n0w + j * 16 + lr;
#pragma unroll
      for (int r = 0; r < 4; ++r)
        Cp[(size_t)(m0 + i * 16 + rr + r) * 256 + col] = acc[i][j][r];
    }
}

// ---------------------------------------------------------------------------
// Attention scoring GEMM: s_out[g] += sum tanh(z@W1 + b1)·w2, fused epilogue.
// grid (64, 6): g = (z,W) pair; BM=64, BN=128 (4 waves x 32 cols), K=256.
// ---------------------------------------------------------------------------
__global__ __launch_bounds__(256) void k_attG(
    const float* __restrict__ cr0, const float* __restrict__ cr1,
    const float* __restrict__ dr0, const float* __restrict__ dr1,
    const unsigned short* __restrict__ Wch, const unsigned short* __restrict__ Wcl,
    const unsigned short* __restrict__ Wdh, const unsigned short* __restrict__ Wdl,
    const float* __restrict__ bc1, const float* __restrict__ wc2,
    const float* __restrict__ bd1, const float* __restrict__ wd2,
    float* __restrict__ s_out) {
  int g = blockIdx.y;
  const float* A = g == 0 ? cr0 : g == 1 ? cr1 : g == 2 ? cr0 : g == 3 ? cr1
                                : g == 4 ? dr0 : dr1;
  const unsigned short* Bh = (g < 2) ? Wch : Wdh;
  const unsigned short* Bl = (g < 2) ? Wcl : Wdl;
  const float* b1 = (g < 2) ? bc1 : bd1;
  const float* w2 = (g < 2) ? wc2 : wd2;
  __shared__ unsigned char sm[2][8192];
  const int tid = threadIdx.x;
  const int m0 = blockIdx.x * 64;
  const int w = tid >> 6, lane = tid & 63;
  const int lr = lane & 15, lk = (lane >> 4) * 8, n0w = w * 32;
  const int srow = tid >> 2, skp = (tid & 3) * 8;
  const int swz = (srow & 7) << 4;
  const int offh = (srow * 128 + skp * 2) ^ swz;
  const int offl = (srow * 128 + 64 + skp * 2) ^ swz;

  auto stage = [&](int b, int kk) {
    const float* p = A + (size_t)(m0 + srow) * 256 + kk + skp;
    float4 x0 = *(const float4*)(p), x1 = *(const float4*)(p + 4);
    float f[8] = {x0.x, x0.y, x0.z, x0.w, x1.x, x1.y, x1.z, x1.w};
    bf16x8 hh, ll;
    split8(f, hh, ll);
    *(bf16x8*)(&sm[b][0] + offh) = hh;
    *(bf16x8*)(&sm[b][0] + offl) = ll;
  };

  f32x4 acc[4][2] = {};
  stage(0, 0);
  __syncthreads();
  for (int s = 0; s < 8; ++s) {
    if (s + 1 < 8) stage((s + 1) & 1, (s + 1) * 32);
    const unsigned char* base = &sm[s & 1][0];
    bf16x8 ah[4], al[4];
#pragma unroll
    for (int i = 0; i < 4; ++i) {
      int row = i * 16 + lr, sz = (row & 7) << 4;
      ah[i] = *(const bf16x8*)(base + ((row * 128 + lk * 2) ^ sz));
      al[i] = *(const bf16x8*)(base + ((row * 128 + 64 + lk * 2) ^ sz));
    }
    int kkg = s * 32 + lk;
#pragma unroll
    for (int j = 0; j < 2; ++j) {
      int col = n0w + j * 16 + lr;
      size_t bo = (size_t)col * 256 + kkg;
      bf16x8 bh = *(const bf16x8*)(Bh + bo);
      bf16x8 bl = *(const bf16x8*)(Bl + bo);
#pragma unroll
      for (int i = 0; i < 4; ++i) {
        acc[i][j] = MFMA16(ah[i], bh, acc[i][j], 0, 0, 0);
        acc[i][j] = MFMA16(ah[i], bl, acc[i][j], 0, 0, 0);
        acc[i][j] = MFMA16(al[i], bh, acc[i][j], 0, 0, 0);
      }
    }
    __syncthreads();
  }
  float tot = 0.f;
#pragma unroll
  for (int j = 0; j < 2; ++j) {
    int col = n0w + j * 16 + lr;
    float bb = b1[col], ww = w2[col];
#pragma unroll
    for (int i = 0; i < 4; ++i)
#pragma unroll
      for (int r = 0; r < 4; ++r) tot += tanhf(acc[i][j][r] + bb) * ww;
  }
  tot = wave_reduce_sum(tot);
  if (lane == 0) atomicAdd(&s_out[g], tot);
}

// ---------------------------------------------------------------------------
// Symmetric dual-Gram + A2 epilogue, both tiles LDS, split ld/wr (T14).
// 1-D grid of 528 upper-tri 128x128 blocks, XCD-bijective swizzle (528%8==0).
// ---------------------------------------------------------------------------
__global__ __launch_bounds__(256, 2) void k_cos2(
    const unsigned short* __restrict__ Ch, const unsigned short* __restrict__ Cl,
    const unsigned short* __restrict__ Dh, const unsigned short* __restrict__ Dl,
    const float* __restrict__ wb, float* __restrict__ rs, float* __restrict__ gP,
    unsigned short* __restrict__ A2h, unsigned short* __restrict__ A2l) {
  int dd = blockIdx.x;
  int b = (dd & 7) * 66 + (dd >> 3);
  int bi = 0, rem = b;
  while (rem >= 32 - bi) { rem -= 32 - bi; ++bi; }
  int bj = bi + rem;
  __shared__ unsigned char sm[2][2][16384];
  const int tid = threadIdx.x;
  const int w = tid >> 6, lane = tid & 63, wm = w >> 1, wn = w & 1;
  const int lr = lane & 15, lk = (lane >> 4) * 8;
  const int rbase = bi * 128, cbase = bj * 128;
  const int row0 = tid >> 2, kp = (tid & 3) * 8;

  auto ldT = [&](const unsigned short* Mh, const unsigned short* Ml, int br, int kk,
                 bf16x8* r) {
#pragma unroll
    for (int ss = 0; ss < 2; ++ss) {
      int row = row0 + ss * 64;
      size_t go = (size_t)(br + row) * 1024 + kk + kp;
      r[ss * 2] = *(const bf16x8*)(Mh + go);
      r[ss * 2 + 1] = *(const bf16x8*)(Ml + go);
    }
  };
  auto wrT = [&](int bb2, int t01, bf16x8* r) {
#pragma unroll
    for (int ss = 0; ss < 2; ++ss) {
      int row = row0 + ss * 64, sz = (row & 7) << 4;
      unsigned char* base = &sm[bb2][t01][0];
      *(bf16x8*)(base + ((row * 128 + kp * 2) ^ sz)) = r[ss * 2];
      *(bf16x8*)(base + ((row * 128 + 64 + kp * 2) ^ sz)) = r[ss * 2 + 1];
    }
  };
  auto gram = [&](const unsigned short* Mh, const unsigned short* Ml, f32x4 (&acc)[4][4]) {
    bf16x8 rA[4], rB[4];
    ldT(Mh, Ml, rbase, 0, rA);
    ldT(Mh, Ml, cbase, 0, rB);
    wrT(0, 0, rA);
    wrT(0, 1, rB);
    __syncthreads();
    for (int s = 0; s < 32; ++s) {
      if (s + 1 < 32) {
        ldT(Mh, Ml, rbase, (s + 1) * 32, rA);
        ldT(Mh, Ml, cbase, (s + 1) * 32, rB);
      }
      const unsigned char* ba = &sm[s & 1][0][0];
      const unsigned char* bb = &sm[s & 1][1][0];
      bf16x8 ah[4], al[4];
#pragma unroll
      for (int i = 0; i < 4; ++i) {
        int row = wm * 64 + i * 16 + lr;
        int sz = (row & 7) << 4;
        ah[i] = *(const bf16x8*)(ba + ((row * 128 + lk * 2) ^ sz));
        al[i] = *(const bf16x8*)(ba + ((row * 128 + 64 + lk * 2) ^ sz));
      }
#pragma unroll
      for (int j = 0; j < 4; ++j) {
        int rowb = wn * 64 + j * 16 + lr;
        int sz = (rowb & 7) << 4;
        bf16x8 bh = *(const bf16x8*)(bb + ((rowb * 128 + lk * 2) ^ sz));
        bf16x8 bl = *(const bf16x8*)(bb + ((rowb * 128 + 64 + lk * 2) ^ sz));
#pragma unroll
        for (int i = 0; i < 4; ++i) {
          acc[i][j] = MFMA16(ah[i], bh, acc[i][j], 0, 0, 0);
          acc[i][j] = MFMA16(ah[i], bl, acc[i][j], 0, 0, 0);
          acc[i][j] = MFMA16(al[i], bh, acc[i][j], 0, 0, 0);
        }
      }
      if (s + 1 < 32) {
        wrT((s + 1) & 1, 0, rA);
        wrT((s + 1) & 1, 1, rB);
      }
      __syncthreads();
    }
  };

  f32x4 aC[4][4] = {}, aD[4][4] = {};
  gram(Ch, Cl, aC);
  gram(Dh, Dl, aD);

  float w0 = wb[0] * 0.125f, w1 = wb[1] * 0.125f;
  int rr = (lane >> 4) * 4;
  bool diag = (bi == bj);
#pragma unroll
  for (int i = 0; i < 4; ++i) {
#pragma unroll
    for (int r = 0; r < 4; ++r) {
      int row = rbase + wm * 64 + i * 16 + rr + r;
      float p = 0.f;
#pragma unroll
      for (int j = 0; j < 4; ++j) {
        int col = cbase + wn * 64 + j * 16 + lr;
        float v = w0 * fmaxf(aC[i][j][r], 0.f) + w1 * fmaxf(aD[i][j][r], 0.f);
        p += v;
        unsigned short h, l;
        split1(v, h, l);
        size_t o = (size_t)row * 4096 + col;
        A2h[o] = h; A2l[o] = l;
        if (diag && row == col) gP[row] = v;
      }
      p += __shfl_xor(p, 1); p += __shfl_xor(p, 2);
      p += __shfl_xor(p, 4); p += __shfl_xor(p, 8);
      if (lr == 0) atomicAdd(&rs[row], p);
    }
  }
  if (!diag) {
#pragma unroll
    for (int j = 0; j < 4; ++j) {
      int col = cbase + wn * 64 + j * 16 + lr;
      float cs = 0.f;
#pragma unroll
      for (int i = 0; i < 4; ++i) {
        int row0m = rbase + wm * 64 + i * 16 + rr;
        ushort4 hv, lv;
#pragma unroll
        for (int r = 0; r < 4; ++r) {
          float v = w0 * fmaxf(aC[i][j][r], 0.f) + w1 * fmaxf(aD[i][j][r], 0.f);
          cs += v;
          unsigned short h, l;
          split1(v, h, l);
          ((unsigned short*)&hv)[r] = h;
          ((unsigned short*)&lv)[r] = l;
        }
        *(ushort4*)(A2h + (size_t)col * 4096 + row0m) = hv;
        *(ushort4*)(A2l + (size_t)col * 4096 + row0m) = lv;
      }
      cs += __shfl_xor(cs, 16); cs += __shfl_xor(cs, 32);
      if (lane < 16) atomicAdd(&rs[col], cs);
    }
  }
}

// ---------------------------------------------------------------------------
// Reduce + epilogue kernels (partials, no atomics)
// ---------------------------------------------------------------------------
__global__ __launch_bounds__(256) void k_redxw(
    const float* __restrict__ part, float* __restrict__ o0, float* __restrict__ o1,
    float* __restrict__ o2, float* __restrict__ o3) {
  int idx = blockIdx.x * 256 + threadIdx.x;
  size_t i4 = (size_t)idx * 4;
  int seg = (int)(i4 >> 20);
  size_t local = i4 & (M1c - 1);
  float4 a = make_float4(0.f, 0.f, 0.f, 0.f);
#pragma unroll
  for (int kb = 0; kb < 2; ++kb) {
    float4 p = *(const float4*)(part + (size_t)(seg * 2 + kb) * M1c + local);
    a.x += p.x; a.y += p.y; a.z += p.z; a.w += p.w;
  }
  float* o = seg == 0 ? o0 : seg == 1 ? o1 : seg == 2 ? o2 : o3;
  *(float4*)(o + local) = a;
}

// adj props: 4 segs x 2 partials + GCN epilogue (KS=2)
__global__ __launch_bounds__(256) void k_ep_prop4(
    const float* __restrict__ part, const float* __restrict__ xwc,
    const float* __restrict__ xwd, const float* __restrict__ dv0,
    const float* __restrict__ dv1, const float* __restrict__ dv2,
    const float* __restrict__ dv3, const float* __restrict__ dg0,
    const float* __restrict__ dg1, const float* __restrict__ dg2,
    const float* __restrict__ dg3, const float* __restrict__ bc,
    const float* __restrict__ bd, float* __restrict__ o0, float* __restrict__ o1,
    float* __restrict__ o2, float* __restrict__ o3) {
  int idx = blockIdx.x * 256 + threadIdx.x;
  size_t i4 = (size_t)idx * 4;
  int seg = (int)(i4 >> 20);
  size_t local = i4 & (M1c - 1);
  int row = (int)(local >> 8), c = (int)(local & 255);
  float4 a = make_float4(0.f, 0.f, 0.f, 0.f);
#pragma unroll
  for (int kb = 0; kb < 2; ++kb) {
    float4 p = *(const float4*)(part + (size_t)(seg * 2 + kb) * M1c + local);
    a.x += p.x; a.y += p.y; a.z += p.z; a.w += p.w;
  }
  const float* xw = (seg < 2) ? xwc : xwd;
  const float* dvec = seg == 0 ? dv0 : seg == 1 ? dv1 : seg == 2 ? dv2 : dv3;
  const float* dgp = seg == 0 ? dg0 : seg == 1 ? dg1 : seg == 2 ? dg2 : dg3;
  const float* bias = (seg < 2) ? bc : bd;
  float* out = seg == 0 ? o0 : seg == 1 ? o1 : seg == 2 ? o2 : o3;
  float4 x = *(const float4*)(xw + local);
  float4 b = *(const float4*)(bias + c);
  float dn = dvec[row], dfix = (1.f - dgp[row]) * dn * dn;
  float4 o;
  o.x = fmaxf(dn * a.x + dfix * x.x + b.x, 0.f);
  o.y = fmaxf(dn * a.y + dfix * x.y + b.y, 0.f);
  o.z = fmaxf(dn * a.z + dfix * x.z + b.z, 0.f);
  o.w = fmaxf(dn * a.w + dfix * x.w + b.w, 0.f);
  *(float4*)(out + local) = o;
}

template <int PRENORM, int SPLITOUT>
__global__ __launch_bounds__(256) void k_ep_prop(
    const float* __restrict__ part, const float* __restrict__ xw,
    const float* __restrict__ dvec, const float* __restrict__ diag,
    const float* __restrict__ bias, float* __restrict__ out,
    unsigned short* __restrict__ oh, unsigned short* __restrict__ ol) {
  int idx = blockIdx.x * 256 + threadIdx.x;
  size_t i = (size_t)idx * 4;
  int row = (int)(i >> 8), c = (int)(i & 255);
  float4 a = make_float4(0.f, 0.f, 0.f, 0.f);
#pragma unroll
  for (int kb = 0; kb < 8; ++kb) {
    float4 p = *(const float4*)(part + (size_t)kb * M1c + i);
    a.x += p.x; a.y += p.y; a.z += p.z; a.w += p.w;
  }
  float4 x = *(const float4*)(xw + i);
  float4 b = *(const float4*)(bias + c);
  float dn = dvec[row], dfix = (1.f - diag[row]) * dn * dn;
  float s = PRENORM ? 1.f : dn;
  float4 o;
  o.x = fmaxf(s * a.x + dfix * x.x + b.x, 0.f);
  o.y = fmaxf(s * a.y + dfix * x.y + b.y, 0.f);
  o.z = fmaxf(s * a.z + dfix * x.z + b.z, 0.f);
  o.w = fmaxf(s * a.w + dfix * x.w + b.w, 0.f);
  *(float4*)(out + i) = o;
  if constexpr (SPLITOUT) {
    ushort4 hv, lv;
    split1(o.x, ((unsigned short*)&hv)[0], ((unsigned short*)&lv)[0]);
    split1(o.y, ((unsigned short*)&hv)[1], ((unsigned short*)&lv)[1]);
    split1(o.z, ((unsigned short*)&hv)[2], ((unsigned short*)&lv)[2]);
    split1(o.w, ((unsigned short*)&hv)[3], ((unsigned short*)&lv)[3]);
    *(ushort4*)(oh + i) = hv;
    *(ushort4*)(ol + i) = lv;
  }
}

__global__ __launch_bounds__(256) void k_red2(const float* __restrict__ part,
                                              float* __restrict__ out) {
  int idx = blockIdx.x * 256 + threadIdx.x;
  size_t i = (size_t)idx * 4;
  float4 p0 = *(const float4*)(part + i);
  float4 p1 = *(const float4*)(part + M1c + i);
  float4 o;
  o.x = p0.x + p1.x; o.y = p0.y + p1.y; o.z = p0.z + p1.z; o.w = p0.w + p1.w;
  *(float4*)(out + i) = o;
}

__global__ __launch_bounds__(256) void k_ep_heads(
    const float* __restrict__ part, const float* __restrict__ b0,
    const float* __restrict__ b1, const float* __restrict__ b2,
    const float* __restrict__ b3, float* __restrict__ o0, float* __restrict__ o1,
    float* __restrict__ o2, float* __restrict__ o3) {
  int idx = blockIdx.x * 256 + threadIdx.x;
  size_t i = (size_t)idx * 4;
  int row = (int)(i >> 8), c = (int)(i & 255);
  int head = c >> 6, cc = c & 63;
  float4 a = make_float4(0.f, 0.f, 0.f, 0.f);
#pragma unroll
  for (int kb = 0; kb < 4; ++kb) {
    float4 p = *(const float4*)(part + (size_t)kb * M1c + i);
    a.x += p.x; a.y += p.y; a.z += p.z; a.w += p.w;
  }
  const float* bias = (head == 0) ? b0 : (head == 1) ? b1 : (head == 2) ? b2 : b3;
  float* outp = (head == 0) ? o0 : (head == 1) ? o1 : (head == 2) ? o2 : o3;
  float4 b = *(const float4*)(bias + cc);
  float4 o;
  o.x = fmaxf(a.x + b.x, 0.f); o.y = fmaxf(a.y + b.y, 0.f);
  o.z = fmaxf(a.z + b.z, 0.f); o.w = fmaxf(a.w + b.w, 0.f);
  if (head & 1) {
    o.x = 1.f / (1.f + expf(-o.x)); o.y = 1.f / (1.f + expf(-o.y));
    o.z = 1.f / (1.f + expf(-o.z)); o.w = 1.f / (1.f + expf(-o.w));
  }
  *(float4*)(outp + (size_t)row * 64 + cc) = o;
}

__global__ void k_beta(const float* __restrict__ s, float* __restrict__ bb) {
  if (threadIdx.x == 0 && blockIdx.x == 0) {
    const float inv = 1.f / 4096.f;
    float c0 = s[0] * inv, c1 = s[1] * inv;
    float m = fmaxf(c0, c1);
    float e0 = expf(c0 - m), e1 = expf(c1 - m);
    float is = 1.f / (e0 + e1);
    bb[0] = e0 * is; bb[1] = e1 * is;
    float d0 = s[2] * inv, d1 = s[3] * inv, d2 = s[4] * inv, d3 = s[5] * inv;
    float md = fmaxf(fmaxf(d0, d1), fmaxf(d2, d3));
    float f0 = expf(d0 - md), f1 = expf(d1 - md), f2 = expf(d2 - md), f3 = expf(d3 - md);
    float id = 1.f / (f0 + f1 + f2 + f3);
    bb[2] = f0 * id; bb[3] = f1 * id; bb[4] = f2 * id; bb[5] = f3 * id;
  }
}

__global__ __launch_bounds__(256) void k_agg(
    const float* __restrict__ cr0, const float* __restrict__ cr1,
    const float* __restrict__ dr0, const float* __restrict__ dr1,
    const float* __restrict__ bb, float* __restrict__ cagg, float* __restrict__ dagg) {
  size_t i = ((size_t)blockIdx.x * 256 + threadIdx.x) * 4;
  float4 a = *(const float4*)(cr0 + i);
  float4 b = *(const float4*)(cr1 + i);
  float4 c = *(const float4*)(dr0 + i);
  float4 d = *(const float4*)(dr1 + i);
  float bc0 = bb[0], bc1 = bb[1], bd0 = bb[2], bd1 = bb[3], bd2 = bb[4], bd3 = bb[5];
  float4 ca, da;
  ca.x = bc0 * a.x + bc1 * b.x; ca.y = bc0 * a.y + bc1 * b.y;
  ca.z = bc0 * a.z + bc1 * b.z; ca.w = bc0 * a.w + bc1 * b.w;
  da.x = bd0 * a.x + bd1 * b.x + bd2 * c.x + bd3 * d.x;
  da.y = bd0 * a.y + bd1 * b.y + bd2 * c.y + bd3 * d.y;
  da.z = bd0 * a.z + bd1 * b.z + bd2 * c.z + bd3 * d.z;
  da.w = bd0 * a.w + bd1 * b.w + bd2 * c.w + bd3 * d.w;
  *(float4*)(cagg + i) = ca;
  *(float4*)(dagg + i) = da;
}

__global__ __launch_bounds__(256) void k_gather(
    const int* __restrict__ xs, const float* __restrict__ U1, const float* __restrict__ U2,
    const float* __restrict__ V1, const float* __restrict__ V2, float* __restrict__ out) {
  int b = blockIdx.x, j = threadIdx.x;
  int row = xs[b];
  size_t r = (size_t)row * 256;
  out[(size_t)b * 512 + j] = 0.5f * (U1[r + j] + U2[r + j]);
  out[(size_t)b * 512 + 256 + j] = 0.5f * (V1[r + j] + V2[r + j]);
}

// ---------------------------------------------------------------------------
extern "C" void kernel_launch(void* const* d_in, const int* in_sizes, int n_in,
                              void* d_out, int out_size, void* d_ws, size_t ws_size,
                              hipStream_t stream) {
  const float* c0adj = (const float*)d_in[0];
  const float* c1adj = (const float*)d_in[1];
  const float* d0adj = (const float*)d_in[2];
  const float* d1adj = (const float*)d_in[3];
  const float* feats = (const float*)d_in[4];
  const float* W_comm = (const float*)d_in[5];
  const float* b_comm = (const float*)d_in[6];
  const float* W_diff = (const float*)d_in[7];
  const float* b_diff = (const float*)d_in[8];
  const float* W_catt1 = (const float*)d_in[9];
  const float* b_catt1 = (const float*)d_in[10];
  const float* w_catt2 = (const float*)d_in[11];
  const float* W_datt1 = (const float*)d_in[12];
  const float* b_datt1 = (const float*)d_in[13];
  const float* w_datt2 = (const float*)d_in[14];
  const float* W_mu_c = (const float*)d_in[15];
  const float* b_mu_c = (const float*)d_in[16];
  const float* W_var_c = (const float*)d_in[17];
  const float* b_var_c = (const float*)d_in[18];
  const float* W_mu_d = (const float*)d_in[19];
  const float* b_mu_d = (const float*)d_in[20];
  const float* W_var_d = (const float*)d_in[21];
  const float* b_var_d = (const float*)d_in[22];
  const float* W_z1_1 = (const float*)d_in[23];
  const float* b_z1_1 = (const float*)d_in[24];
  const float* W_z1_2 = (const float*)d_in[25];
  const float* b_z1_2 = (const float*)d_in[26];
  const float* wb_z1 = (const float*)d_in[27];
  const float* Wt_c = (const float*)d_in[28];
  const float* Wt_d = (const float*)d_in[29];
  const float* W_z2_1 = (const float*)d_in[30];
  const float* b_z2_1 = (const float*)d_in[31];
  const float* W_z2_2 = (const float*)d_in[32];
  const float* b_z2_2 = (const float*)d_in[33];
  const float* wb_z2 = (const float*)d_in[34];
  const int* xs = (const int*)d_in[35];

  float* out = (float*)d_out;
  float* out_muc = out + 65536;
  float* out_varc = out + 327680;
  float* out_mud = out + 589824;
  float* out_vard = out + 851968;

  float* ws = (float*)d_ws;
  const size_t M1 = M1c;
  float* xw_comm = ws + 0 * M1;
  float* xw_diff = ws + 1 * M1;
  float* xw_z1 = ws + 2 * M1;
  float* xw_z2 = ws + 3 * M1;
  float* cr0 = ws + 4 * M1;
  float* cr1 = ws + 5 * M1;
  float* dr0 = ws + 6 * M1;
  float* dr1 = ws + 7 * M1;
  float* u1 = ws + 8 * M1;
  float* u2 = ws + 9 * M1;
  float* v1 = ws + 10 * M1;
  float* v2 = ws + 11 * M1;
  float* uw = ws + 12 * M1;
  float* cagg = ws + 13 * M1;
  float* dagg = ws + 14 * M1;
  float* accb4 = ws + 15 * M1;  // slots 15-18 (small partials: uw/heads)
  unsigned short* B4h[4];
  unsigned short* B4l[4];
  for (int t = 0; t < 4; ++t) {  // slots 19-22 (B pairs, 1 slot each)
    B4h[t] = (unsigned short*)(ws + (19 + t) * M1);
    B4l[t] = B4h[t] + (size_t)256 * 4096;
  }
  unsigned short* A1h = (unsigned short*)(ws + 23 * M1);  // slots 23-30
  unsigned short* A1l = (unsigned short*)(ws + 31 * M1);  // slots 31-38
  unsigned short* Cch = (unsigned short*)(ws + 23 * M1);  // overlay dead A1h
  unsigned short* Ccl = (unsigned short*)(ws + 25 * M1);
  unsigned short* Cdh = (unsigned short*)(ws + 27 * M1);
  unsigned short* Cdl = (unsigned short*)(ws + 29 * M1);
  float* partZ2 = ws + 31 * M1;  // 8 slots (dead A1l, during z2)
  float* tmpb = ws + 39 * M1;    // 16 slots
  float* part16 = ws + 39 * M1;  // prop partials (pre-cos2)
  float* partZ1 = ws + 39 * M1;  // z1 partials (pre-cos2)
  unsigned short* A2h = (unsigned short*)(ws + 39 * M1);  // cos2 output overlays
  unsigned short* A2l = (unsigned short*)(ws + 47 * M1);
  unsigned short* u1h = (unsigned short*)(ws + 55 * M1);
  unsigned short* u1l = u1h + (size_t)4096 * 256;
  unsigned short* v1h = (unsigned short*)(ws + 56 * M1);
  unsigned short* v1l = v1h + (size_t)4096 * 256;
  float* vecs = ws + 57 * M1;
#define VV(i) (vecs + (size_t)(i) * 4096)
  float* rs_c0 = VV(0); float* rs_c1 = VV(1); float* rs_d0 = VV(2); float* rs_d1 = VV(3);
  float* dg_c0 = VV(4); float* dg_c1 = VV(5); float* dg_d0 = VV(6); float* dg_d1 = VV(7);
  float* cs_tmp = VV(8); float* rs_A2 = VV(9);
  float* d_c0 = VV(10); float* d_c1 = VV(11); float* d_dd0 = VV(12); float* d_dd1 = VV(13);
  float* d_A1 = VV(14); float* d_A2 = VV(15);
  float* gP_dd0 = VV(16); float* gP_dd1 = VV(17); float* gP_A1 = VV(18); float* gP_A2 = VV(19);
  float* satt = VV(20);
  float* beta = satt + 8;

  hipMemsetAsync(cs_tmp, 0, 2 * 4096 * sizeof(float), stream);  // cs_tmp + rs_A2
  hipMemsetAsync(satt, 0, 64, stream);

  // adjacency pass
  k_rowsums<<<1024, 256, 0, stream>>>(c0adj, c1adj, d0adj, d1adj, wb_z1, tmpb,
                                      rs_c0, rs_c1, rs_d0, rs_d1, dg_c0, dg_c1, dg_d0, dg_d1);
  k_colsum<<<dim3(4, 32), 256, 0, stream>>>(tmpb, cs_tmp);
  k_fin<<<16, 256, 0, stream>>>(rs_c0, rs_c1, rs_d0, rs_d1, dg_c0, dg_c1, dg_d0, dg_d1,
                                cs_tmp, wb_z1, d_c0, d_c1, d_dd0, d_dd1, d_A1,
                                gP_dd0, gP_dd1, gP_A1);
  k_addTn<<<dim3(64, 64), 256, 0, stream>>>(tmpb, d_A1, A1h, A1l);

  // fused feats @ W: K=512, KS=2, Kc=256 -> 8 partials -> xw
  k_prepB<<<dim3(8, 4), 256, 0, stream>>>(W_comm, nullptr, B4h[0], B4l[0], 512, 256);
  k_prepB<<<dim3(8, 4), 256, 0, stream>>>(W_diff, nullptr, B4h[1], B4l[1], 512, 256);
  k_prepB<<<dim3(8, 4), 256, 0, stream>>>(W_z1_1, nullptr, B4h[2], B4l[2], 512, 256);
  k_prepB<<<dim3(8, 4), 256, 0, stream>>>(W_z2_1, nullptr, B4h[3], B4l[3], 512, 256);
  k_prop4S<<<512, 256, 0, stream>>>(
      feats, feats, feats, feats, feats, feats, 0,
      nullptr, nullptr, nullptr, nullptr,
      B4h[0], B4l[0], B4h[1], B4l[1], B4h[2], B4l[2], B4h[3], B4l[3],
      part16, 512, 256, 2);
  k_redxw<<<4096, 256, 0, stream>>>(part16, xw_comm, xw_diff, xw_z1, xw_z2);

  // fused adjacency props: KS=2 (Kc=2048), shared B panels, k-scale at A-staging
  k_prepB<<<dim3(64, 4), 256, 0, stream>>>(xw_comm, nullptr, B4h[0], B4l[0], 4096, 256);
  k_prepB<<<dim3(64, 4), 256, 0, stream>>>(xw_diff, nullptr, B4h[1], B4l[1], 4096, 256);
  k_prop4S<<<512, 256, 0, stream>>>(
      c0adj, c1adj, d0adj, d1adj, c0adj, c1adj, 0xC,
      d_c0, d_c1, d_dd0, d_dd1,
      B4h[0], B4l[0], B4h[0], B4l[0], B4h[1], B4l[1], B4h[1], B4l[1],
      part16, 4096, 2048, 2);
  k_ep_prop4<<<4096, 256, 0, stream>>>(part16, xw_comm, xw_diff, d_c0, d_c1, d_dd0, d_dd1,
                                       dg_c0, dg_c1, gP_dd0, gP_dd1, b_comm, b_diff,
                                       cr0, cr1, dr0, dr1);

  unsigned short* Bth = B4h[0];
  unsigned short* BtlL = Bth + (size_t)256 * 4096;
  unsigned short* BthS = Bth;
  unsigned short* BtlS = Bth + (size_t)256 * 256;

  // ---- z1 branch (before cos2; uses A1, partials in pre-A2 region) ----
  k_prepB<<<dim3(64, 4), 256, 0, stream>>>(xw_z1, nullptr, Bth, BtlL, 4096, 256);
  k_gemmS<<<512, 256, 0, stream>>>(A1h, A1l, Bth, BtlL, partZ1, 4096, 512);
  k_ep_prop<1, 1><<<1024, 256, 0, stream>>>(partZ1, xw_z1, d_A1, gP_A1, b_z1_1, u1, u1h, u1l);
  k_prepB<<<dim3(4, 4), 256, 0, stream>>>(W_z1_2, nullptr, BthS, BtlS, 256, 256);
  k_gemmS<<<128, 256, 0, stream>>>(u1h, u1l, BthS, BtlS, accb4, 256, 128);
  k_red2<<<1024, 256, 0, stream>>>(accb4, uw);
  k_prepB<<<dim3(64, 4), 256, 0, stream>>>(uw, nullptr, Bth, BtlL, 4096, 256);
  k_gemmS<<<512, 256, 0, stream>>>(A1h, A1l, Bth, BtlL, partZ1, 4096, 512);
  k_ep_prop<1, 0><<<1024, 256, 0, stream>>>(partZ1, uw, d_A1, gP_A1, b_z1_2, u2, nullptr, nullptr);

  // attention scoring via MFMA (fused tanh·w2 reduce), then beta + agg
  {
    unsigned short* Wch = B4h[1];
    unsigned short* Wcl = Wch + (size_t)128 * 256;
    unsigned short* Wdh = B4h[2];
    unsigned short* Wdl = Wdh + (size_t)128 * 256;
    k_prepB<<<dim3(4, 2), 256, 0, stream>>>(W_catt1, nullptr, Wch, Wcl, 256, 128);
    k_prepB<<<dim3(4, 2), 256, 0, stream>>>(W_datt1, nullptr, Wdh, Wdl, 256, 128);
    k_attG<<<dim3(64, 6), 256, 0, stream>>>(cr0, cr1, dr0, dr1, Wch, Wcl, Wdh, Wdl,
                                            b_catt1, w_catt2, b_datt1, w_datt2, satt);
  }
  k_beta<<<1, 64, 0, stream>>>(satt, beta);
  k_agg<<<1024, 256, 0, stream>>>(cr0, cr1, dr0, dr1, beta, cagg, dagg);

  // heads: dual-A GEMM (KS=4, partials in accb4)
  {
    unsigned short* Hh = B4h[0];
    unsigned short* Hl = Hh + (size_t)256 * 256;
    k_prepB<<<dim3(4, 1), 256, 0, stream>>>(W_mu_c, nullptr, Hh + 0 * 64 * 256, Hl + 0 * 64 * 256, 256, 64);
    k_prepB<<<dim3(4, 1), 256, 0, stream>>>(W_var_c, nullptr, Hh + 1 * 64 * 256, Hl + 1 * 64 * 256, 256, 64);
    k_prepB<<<dim3(4, 1), 256, 0, stream>>>(W_mu_d, nullptr, Hh + 2 * 64 * 256, Hl + 2 * 64 * 256, 256, 64);
    k_prepB<<<dim3(4, 1), 256, 0, stream>>>(W_var_d, nullptr, Hh + 3 * 64 * 256, Hl + 3 * 64 * 256, 256, 64);
    k_gemmH<<<dim3(4, 64), 256, 0, stream>>>(cagg, dagg, Hh, Hl, accb4, 256, 64);
    k_ep_heads<<<1024, 256, 0, stream>>>(accb4, b_mu_c, b_var_c, b_mu_d, b_var_d,
                                         out_muc, out_varc, out_mud, out_vard);
  }

  // cosine contexts -> split pairs (dead A1h region), one dispatch
  k_cn2<<<32768, 256, 0, stream>>>(out_muc, Wt_c, out_mud, Wt_d, Cch, Ccl, Cdh, Cdl);

  // A2 (symmetric dual-Gram, compact 528-block upper-tri grid, XCD swizzle)
  k_cos2<<<528, 256, 0, stream>>>(Cch, Ccl, Cdh, Cdl, wb_z2, rs_A2, gP_A2, A2h, A2l);
  k_dA2<<<16, 256, 0, stream>>>(rs_A2, gP_A2, d_A2);

  // ---- z2 branch (partials in dead A1l region) ----
  k_prepB<<<dim3(64, 4), 256, 0, stream>>>(xw_z2, d_A2, Bth, BtlL, 4096, 256);
  k_gemmS<<<512, 256, 0, stream>>>(A2h, A2l, Bth, BtlL, partZ2, 4096, 512);
  k_ep_prop<0, 1><<<1024, 256, 0, stream>>>(partZ2, xw_z2, d_A2, gP_A2, b_z2_1, v1, v1h, v1l);
  k_prepB<<<dim3(4, 4), 256, 0, stream>>>(W_z2_2, nullptr, BthS, BtlS, 256, 256);
  k_gemmS<<<128, 256, 0, stream>>>(v1h, v1l, BthS, BtlS, accb4, 256, 128);
  k_red2<<<1024, 256, 0, stream>>>(accb4, uw);
  k_prepB<<<dim3(64, 4), 256, 0, stream>>>(uw, d_A2, Bth, BtlL, 4096, 256);
  k_gemmS<<<512, 256, 0, stream>>>(A2h, A2l, Bth, BtlL, partZ2, 4096, 512);
  k_ep_prop<0, 0><<<1024, 256, 0, stream>>>(partZ2, uw, d_A2, gP_A2, b_z2_2, v2, nullptr, nullptr);

  // h[xs]
  k_gather<<<128, 256, 0, stream>>>(xs, u1, u2, v1, v2, out);
}